// Round 11
// baseline (9721.532 us; speedup 1.0000x reference)
//
#include <hip/hip_runtime.h>
#include <hip/hip_bf16.h>
#include <math.h>

// Problem constants (B=32, Ts=64, Tt=66, E=H=512, V=16000)
#define TSRC 64
#define TTRG 66
#define NVOC 15996   // V-4
#define NTILE 125    // ceil(15996/128)

__device__ __forceinline__ float sigm(float x){ return 1.f/(1.f+expf(-x)); }

// Monotone-counter grid barrier (validated round 10: absmax 0.0).
__device__ __forceinline__ void grid_barrier(unsigned* cnt, unsigned nblk, unsigned& mygen)
{
  __syncthreads();
  if (threadIdx.x == 0) {
    __threadfence();
    atomicAdd(cnt, 1u);
    unsigned target = nblk * (mygen + 1u);
    while (__hip_atomic_load(cnt, __ATOMIC_RELAXED, __HIP_MEMORY_SCOPE_AGENT) < target)
      __builtin_amdgcn_s_sleep(4);
    __threadfence();
  }
  __syncthreads();
  mygen += 1u;
}

// ---------------------------------------------------------------------------
// Tiled GEMM: C = A[M,K] * B[N,K]^T (+bias, optional tanh epilogue).
// ---------------------------------------------------------------------------
struct GArgs {
  const float* A;  int lda;
  const float* Bw; int ldb;
  const float* bias;
  float* C; int ldc;
  int N; int K; int nNb; int act;
};

template<int BM,int BN,int BK,int TM,int TN>
__global__ __launch_bounds__(256)
void k_gemm(GArgs a)
{
  const int tid = threadIdx.x;
  const int mb = blockIdx.x / a.nNb;
  const int nb = blockIdx.x % a.nNb;
  const int m0 = mb*BM, n0 = nb*BN;
  const float* A  = a.A + (size_t)m0*a.lda;
  const float* Bw = a.Bw;

  __shared__ float As[BK][BM+1];
  __shared__ float Bs[BK][BN+4];
  const int tx = tid % (BN/TN);
  const int ty = tid / (BN/TN);
  float acc[TM][TN];
  #pragma unroll
  for (int i=0;i<TM;i++)
    #pragma unroll
    for (int j=0;j<TN;j++) acc[i][j]=0.f;

  for (int kt=0; kt<a.K; kt+=BK) {
    #pragma unroll
    for (int i=tid; i<BM*BK; i+=256) {
      int m = i/BK, k = i%BK;
      As[k][m] = A[(size_t)m*a.lda + kt + k];
    }
    #pragma unroll
    for (int i=tid; i<BN*BK; i+=256) {
      int n = i/BK, k = i%BK;
      int gn = n0+n;
      Bs[k][n] = (gn < a.N) ? Bw[(size_t)gn*a.ldb + kt + k] : 0.f;
    }
    __syncthreads();
    #pragma unroll
    for (int k=0;k<BK;k++) {
      float av[TM], bv[TN];
      #pragma unroll
      for (int i=0;i<TM;i++) av[i]=As[k][ty*TM+i];
      #pragma unroll
      for (int j=0;j<TN;j++) bv[j]=Bs[k][tx*TN+j];
      #pragma unroll
      for (int i=0;i<TM;i++)
        #pragma unroll
        for (int j=0;j<TN;j++)
          acc[i][j] = fmaf(av[i], bv[j], acc[i][j]);
    }
    __syncthreads();
  }
  #pragma unroll
  for (int i=0;i<TM;i++) {
    int m = m0 + ty*TM + i;
    #pragma unroll
    for (int j=0;j<TN;j++) {
      int n = n0 + tx*TN + j;
      if (n < a.N) {
        float v = acc[i][j];
        if (a.bias) v += a.bias[n];
        if (a.act)  v = tanhf(v);
        a.C[(size_t)m*a.ldc + n] = v;
      }
    }
  }
}

// ---------------------------------------------------------------------------
// Fused logits GEMM + per-tile row reduction (never materializes logits).
// ---------------------------------------------------------------------------
__global__ __launch_bounds__(256)
void k_logits(const float* __restrict__ A, const float* __restrict__ Bw,
              const int* __restrict__ trg,
              float* __restrict__ Pmax, int* __restrict__ Parg,
              float* __restrict__ Psum, float* __restrict__ Ltgt)
{
  const int tid = threadIdx.x;
  const int mb = blockIdx.x / NTILE;
  const int nb = blockIdx.x % NTILE;
  const int m0 = mb*128, n0 = nb*128;

  __shared__ float As[16][129];
  __shared__ float Bs[16][132];
  const int tx = tid & 15;
  const int ty = tid >> 4;
  float acc[8][8];
  #pragma unroll
  for (int i=0;i<8;i++)
    #pragma unroll
    for (int j=0;j<8;j++) acc[i][j]=0.f;

  for (int kt=0; kt<512; kt+=16) {
    #pragma unroll
    for (int i=tid; i<128*16; i+=256) {
      int m = i>>4, k = i&15;
      As[k][m] = A[(size_t)(m0+m)*512 + kt + k];
    }
    #pragma unroll
    for (int i=tid; i<128*16; i+=256) {
      int n = i>>4, k = i&15;
      int gn = n0+n;
      Bs[k][n] = (gn < NVOC) ? Bw[(size_t)gn*512 + kt + k] : 0.f;
    }
    __syncthreads();
    #pragma unroll
    for (int k=0;k<16;k++) {
      float av[8], bv[8];
      #pragma unroll
      for (int i=0;i<8;i++) av[i]=As[k][ty*8+i];
      #pragma unroll
      for (int j=0;j<8;j++) bv[j]=Bs[k][tx*8+j];
      #pragma unroll
      for (int i=0;i<8;i++)
        #pragma unroll
        for (int j=0;j<8;j++)
          acc[i][j] = fmaf(av[i], bv[j], acc[i][j]);
    }
    __syncthreads();
  }

  #pragma unroll
  for (int i=0;i<8;i++) {
    int r = m0 + ty*8 + i;                 // global row (= step*32 + b)
    int step = r >> 5, b = r & 31;
    int tgt = trg[b*TTRG + step + 1];
    int ti = tgt - 4;
    float m = -3.4e38f; int am = 0x7fffffff;
    #pragma unroll
    for (int j=0;j<8;j++) {
      int gn = n0 + tx*8 + j;
      if (gn < NVOC) {
        float x = acc[i][j];
        if (x > m || (x == m && gn < am)) { m = x; am = gn; }
      }
    }
    float s = 0.f;
    float lt = 0.f;
    #pragma unroll
    for (int j=0;j<8;j++) {
      int gn = n0 + tx*8 + j;
      if (gn < NVOC) {
        s += expf(acc[i][j] - m);
        if (gn == ti) lt = acc[i][j];
      }
    }
    #pragma unroll
    for (int d=1; d<16; d<<=1) {
      float m2 = __shfl_xor(m, d);
      int   a2 = __shfl_xor(am, d);
      float s2 = __shfl_xor(s, d);
      float l2 = __shfl_xor(lt, d);
      float M = fmaxf(m, m2);
      s = s*expf(m - M) + s2*expf(m2 - M);
      if (m2 > m || (m2 == m && a2 < am)) am = a2;
      m = M;
      lt += l2;
    }
    if (tx == 0) {
      size_t pi = (size_t)r*NTILE + nb;
      Pmax[pi] = m; Parg[pi] = am; Psum[pi] = s;
      if (ti >= n0 && ti < n0 + 128) Ltgt[r] = lt;
    }
  }
}

// Combine per-tile partials -> nll + pred per row.
__global__ __launch_bounds__(128)
void k_combine(const float* __restrict__ Pmax, const int* __restrict__ Parg,
               const float* __restrict__ Psum, const float* __restrict__ Ltgt,
               const int* __restrict__ trg,
               float* __restrict__ nll, float* __restrict__ outp)
{
  int r = blockIdx.x;
  int step = r >> 5, b = r & 31;
  int tid = threadIdx.x;
  __shared__ float sm[128]; __shared__ int sa[128]; __shared__ float ssum[128];
  float m = -3.4e38f; int am = 0x7fffffff; float s = 0.f;
  if (tid < NTILE) {
    size_t pi = (size_t)r*NTILE + tid;
    m = Pmax[pi]; am = Parg[pi]; s = Psum[pi];
  }
  sm[tid]=m; sa[tid]=am; ssum[tid]=s; __syncthreads();
  for (int off=64; off; off>>=1) {
    if (tid < off) {
      float m2 = sm[tid+off]; int a2 = sa[tid+off]; float s2 = ssum[tid+off];
      float m1 = sm[tid];     int a1 = sa[tid];     float s1 = ssum[tid];
      float M = fmaxf(m1, m2);
      ssum[tid] = s1*expf(m1 - M) + s2*expf(m2 - M);
      if (m2 > m1 || (m2 == m1 && a2 < a1)) sa[tid] = a2;
      sm[tid] = M;
    }
    __syncthreads();
  }
  if (tid == 0) {
    int tgt = trg[b*TTRG + step + 1];
    float nl = 0.f;
    if (tgt != 0) nl = -(Ltgt[r] - sm[0] - logf(ssum[0]));
    nll[step*32 + b] = nl;
    outp[1 + b*64 + step] = (float)(sa[0] + 4);
  }
}

// Embedding gather
__global__ void k_gather(const float* __restrict__ emb, const int* __restrict__ tok,
                         float* __restrict__ outp, int Tfull)
{
  int r = blockIdx.x;
  int t = r >> 5, b = r & 31;
  int token = tok[b*Tfull + t];
  const float4* s = (const float4*)(emb + (size_t)token*512);
  float4* d = (float4*)(outp + (size_t)r*512);
  d[threadIdx.x] = s[threadIdx.x];
}

// ---------------------------------------------------------------------------
// PERSISTENT encoder layer v3: weights LDS-resident, no K-split partials,
// one barrier/step. grid 256: dir = bid>>7, block owns 4 hidden j x 4 gates,
// full K=512. Thread (r=tid>>4 in [0,16), bh=tid&15) -> 2 batch cols.
// ---------------------------------------------------------------------------
__global__ __launch_bounds__(256)
void k_enc_layer(const float* __restrict__ Whh,   // [2][2048][512]
                 const float* __restrict__ xg,    // [2048][4096]
                 float* __restrict__ hA, float* __restrict__ hB,
                 float* __restrict__ cst,         // [2*32][512]
                 float* __restrict__ xout, int mode,
                 unsigned* __restrict__ cnt)
{
  const int bid = blockIdx.x;
  const int dir = bid >> 7;
  const int j0  = (bid & 127) * 4;
  const int tid = threadIdx.x;
  const int r   = tid >> 4;      // gate-row in block: g*4 + jj
  const int bh  = tid & 15;
  __shared__ float wlds[16*512];
  __shared__ float hs[128][34];
  __shared__ float glds[16][33];
  unsigned mygen = 0;

  // stage weight slice once: 16 rows x 512
  {
    const float4* W4 = (const float4*)(Whh + (size_t)dir*2048*512);
    float4* wl4 = (float4*)wlds;
    for (int idx=tid; idx<16*128; idx+=256) {
      int rr = idx >> 7, cq = idx & 127;
      int g = rr >> 2, jj = rr & 3;
      wl4[rr*128 + cq] = W4[(size_t)(g*512 + j0 + jj)*128 + cq];
    }
  }
  __syncthreads();

  for (int s = 0; s < 64; ++s) {
    const float* hin = ((s&1) ? hB : hA) + (size_t)dir*32*512;
    float* hout      = ((s&1) ? hA : hB);
    float acc0 = 0.f, acc1 = 0.f;
    for (int kc = 0; kc < 4; ++kc) {
      const float4* H4 = (const float4*)hin;
      for (int idx=tid; idx<1024; idx+=256) {
        int b = idx >> 5, kq = idx & 31;
        float4 v = H4[(size_t)b*128 + kc*32 + kq];
        hs[kq*4+0][b] = v.x; hs[kq*4+1][b] = v.y;
        hs[kq*4+2][b] = v.z; hs[kq*4+3][b] = v.w;
      }
      __syncthreads();
      const float* wrow = wlds + r*512 + kc*128;
      #pragma unroll 8
      for (int k=0;k<128;k++) {
        float wv = wrow[k];
        acc0 = fmaf(wv, hs[k][bh*2+0], acc0);
        acc1 = fmaf(wv, hs[k][bh*2+1], acc1);
      }
      __syncthreads();
    }
    glds[r][bh*2+0] = acc0;
    glds[r][bh*2+1] = acc1;
    __syncthreads();
    if (tid < 128) {
      int jj = tid >> 5, b = tid & 31;
      int jh = j0 + jj;
      int tt = dir ? (63 - s) : s;
      const float* x = xg + ((size_t)tt*32 + b)*4096 + dir*2048;
      float gi = glds[0*4+jj][b] + x[jh];
      float gf = glds[1*4+jj][b] + x[512+jh];
      float gg = glds[2*4+jj][b] + x[1024+jh];
      float go = glds[3*4+jj][b] + x[1536+jh];
      size_t ci = ((size_t)dir*32 + b)*512 + jh;
      float cn = sigm(gf)*cst[ci] + sigm(gi)*tanhf(gg);
      float hn = sigm(go)*tanhf(cn);
      cst[ci] = cn;
      hout[ci] = hn;
      if (mode == 0) xout[((size_t)tt*32 + b)*1024 + dir*512 + jh] = hn;  // x1
      else           xout[((size_t)b*64 + tt)*1024 + dir*512 + jh] = hn;  // enc_out
    }
    grid_barrier(cnt, 256u, mygen);
  }
}

// Pack layer-0 final states into decoder initial h/c
__global__ void k_pack(const float* __restrict__ hfin, const float* __restrict__ cfin,
                       float* __restrict__ dh, float* __restrict__ dcc)
{
  int tid = blockIdx.x*256 + threadIdx.x;   // 32768
  int j = tid & 1023, b = tid >> 10;
  int dir = j >> 9, jj = j & 511;
  size_t si = ((size_t)dir*32 + b)*512 + jj;
  dh[(size_t)b*1024 + j]  = hfin[si];
  dcc[(size_t)b*1024 + j] = cfin[si];
}

// ---------------------------------------------------------------------------
// PERSISTENT decoder phase A v3: same structure, K=1024.
// grid 256: block owns hidden j0=bid*4 .. +3 (x4 gates), all K.
// ---------------------------------------------------------------------------
__global__ __launch_bounds__(256)
void k_dec_layer(const float* __restrict__ Whh,   // [4096][1024]
                 const float* __restrict__ xg,    // [64][32][4096]
                 const float* __restrict__ dh0,   // [32][1024]
                 float* __restrict__ cst,         // [32][1024]
                 float* __restrict__ Hall,        // [64][32][1024]
                 const int* __restrict__ trg,
                 unsigned* __restrict__ cnt)
{
  const int bid = blockIdx.x;
  const int j0  = bid*4;
  const int tid = threadIdx.x;
  const int r   = tid >> 4;
  const int bh  = tid & 15;
  __shared__ float wlds[16*1024];
  __shared__ float hs[128][34];
  __shared__ float glds[16][33];
  unsigned mygen = 0;

  {
    const float4* W4 = (const float4*)Whh;
    float4* wl4 = (float4*)wlds;
    for (int idx=tid; idx<16*256; idx+=256) {
      int rr = idx >> 8, cq = idx & 255;
      int g = rr >> 2, jj = rr & 3;
      wl4[rr*256 + cq] = W4[(size_t)(g*1024 + j0 + jj)*256 + cq];
    }
  }
  __syncthreads();

  for (int st = 0; st < 64; ++st) {
    const float* H = (st == 0) ? dh0 : (Hall + (size_t)(st-1)*32768);
    float acc0 = 0.f, acc1 = 0.f;
    for (int kc = 0; kc < 8; ++kc) {
      const float4* H4 = (const float4*)H;
      for (int idx=tid; idx<1024; idx+=256) {
        int b = idx >> 5, kq = idx & 31;
        float4 v = H4[(size_t)b*256 + kc*32 + kq];
        hs[kq*4+0][b] = v.x; hs[kq*4+1][b] = v.y;
        hs[kq*4+2][b] = v.z; hs[kq*4+3][b] = v.w;
      }
      __syncthreads();
      const float* wrow = wlds + r*1024 + kc*128;
      #pragma unroll 8
      for (int k=0;k<128;k++) {
        float wv = wrow[k];
        acc0 = fmaf(wv, hs[k][bh*2+0], acc0);
        acc1 = fmaf(wv, hs[k][bh*2+1], acc1);
      }
      __syncthreads();
    }
    glds[r][bh*2+0] = acc0;
    glds[r][bh*2+1] = acc1;
    __syncthreads();
    if (tid < 128) {
      int jj = tid >> 5, b = tid & 31;
      int jh = j0 + jj;
      int tgt = trg[b*TTRG + st + 1];
      bool dm = (tgt == 0);
      const float* x = xg + (size_t)st*131072 + (size_t)b*4096;
      float gi = glds[0*4+jj][b] + x[jh];
      float gf = glds[1*4+jj][b] + x[1024+jh];
      float gg = glds[2*4+jj][b] + x[2048+jh];
      float go = glds[3*4+jj][b] + x[3072+jh];
      size_t ci = (size_t)b*1024 + jh;
      float cn = sigm(gf)*cst[ci] + sigm(gi)*tanhf(gg);
      float hn = sigm(go)*tanhf(cn);
      cst[ci] = cn;                                   // cell NOT masked
      Hall[(size_t)st*32768 + ci] = dm ? 0.f : hn;    // h masked
    }
    grid_barrier(cnt, 256u, mygen);
  }
}

// ---------------------------------------------------------------------------
// Batched attention (phase B)
// ---------------------------------------------------------------------------
__global__ __launch_bounds__(256)
void k_attn(const float* __restrict__ Hall,    // [64][32][1024]
            const float* __restrict__ encout,  // [32][64][1024]
            const int* __restrict__ src,
            float* __restrict__ hctx)          // [2048][2048]
{
  int bid = blockIdx.x;
  int t = bid >> 5, b = bid & 31;
  int tid = threadIdx.x;
  __shared__ float sh[1024];
  __shared__ float ssc[64];
  const float* h = Hall + ((size_t)t*32 + b)*1024;
  size_t row = (size_t)t*32 + b;
  #pragma unroll
  for (int r=0;r<4;r++) {
    int jh = tid + 256*r;
    float v = h[jh];
    sh[jh] = v;
    hctx[row*2048 + jh] = v;
  }
  __syncthreads();
  {
    int tq = tid >> 2, part = tid & 3;
    const float* eo = encout + ((size_t)b*64 + tq)*1024 + part*256;
    const float* hh = sh + part*256;
    float s = 0.f;
    for (int k=0;k<256;k++) s = fmaf(hh[k], eo[k], s);
    s += __shfl_xor(s, 1);
    s += __shfl_xor(s, 2);
    if (part == 0) ssc[tq] = (src[b*TSRC + tq] == 0) ? -1e9f : s;
  }
  __syncthreads();
  if (tid < 64) {
    float v = ssc[tid];
    float m = v;
    for (int d=1; d<64; d<<=1) m = fmaxf(m, __shfl_xor(m, d));
    float e = expf(v - m);
    float su = e;
    for (int d=1; d<64; d<<=1) su += __shfl_xor(su, d);
    ssc[tid] = e / su;
  }
  __syncthreads();
  #pragma unroll
  for (int r=0;r<4;r++) {
    int k = tid + 256*r;
    float a = 0.f;
    const float* eb = encout + (size_t)b*65536 + k;
    for (int tt=0;tt<64;tt++) a = fmaf(ssc[tt], eb[tt*1024], a);
    hctx[row*2048 + 1024 + k] = a;
  }
}

// Final: loss = sum(nll)/denom
__global__ __launch_bounds__(256)
void k_final(const float* __restrict__ nll, const int* __restrict__ trg,
             float* __restrict__ outp)
{
  int tid = threadIdx.x;
  __shared__ float ss[256]; __shared__ int sc[256];
  float s = 0.f; int cnt = 0;
  for (int i=tid; i<2048; i+=256) {
    s += nll[i];
    int b = i >> 6, t = (i & 63) + 1;
    cnt += (trg[b*TTRG + t] != 0);
  }
  ss[tid]=s; sc[tid]=cnt; __syncthreads();
  for (int off=128; off; off>>=1) {
    if (tid<off) { ss[tid]+=ss[tid+off]; sc[tid]+=sc[tid+off]; }
    __syncthreads();
  }
  if (tid==0) outp[0] = ss[0] / (float)sc[0];
}

// ---------------------------------------------------------------------------
static void launch_big(hipStream_t st, const float* A, int lda,
                       const float* Bw, int ldb, const float* bias,
                       float* C, int ldc, int M, int N, int K, int act)
{
  GArgs a;
  a.A=A; a.lda=lda;
  a.Bw=Bw; a.ldb=ldb;
  a.bias=bias;
  a.C=C; a.ldc=ldc;
  a.N=N; a.K=K; a.nNb=(N+127)/128; a.act=act;
  dim3 g((M/128)*a.nNb, 1, 1);
  k_gemm<128,128,16,8,8><<<g, dim3(256), 0, st>>>(a);
}

static void launch_med(hipStream_t st, const float* A, int lda,
                       const float* Bw, int ldb, const float* bias,
                       float* C, int ldc, int M, int N, int K, int act)
{
  GArgs a;
  a.A=A; a.lda=lda;
  a.Bw=Bw; a.ldb=ldb;
  a.bias=bias;
  a.C=C; a.ldc=ldc;
  a.N=N; a.K=K; a.nNb=(N+63)/64; a.act=act;
  dim3 g((M/64)*a.nNb, 1, 1);
  k_gemm<64,64,16,4,4><<<g, dim3(256), 0, st>>>(a);
}

extern "C" void kernel_launch(void* const* d_in, const int* in_sizes, int n_in,
                              void* d_out, int out_size, void* d_ws, size_t ws_size,
                              hipStream_t stream)
{
  (void)in_sizes; (void)n_in; (void)out_size; (void)ws_size;
  const int*   src   = (const int*)  d_in[0];
  const int*   trg   = (const int*)  d_in[1];
  const float* semb  = (const float*)d_in[2];
  const float* temb  = (const float*)d_in[3];
  const float* e0Wih = (const float*)d_in[4];
  const float* e0Whh = (const float*)d_in[5];
  const float* e0b   = (const float*)d_in[6];
  const float* e1Wih = (const float*)d_in[7];
  const float* e1Whh = (const float*)d_in[8];
  const float* e1b   = (const float*)d_in[9];
  const float* dWih  = (const float*)d_in[10];
  const float* dWhh  = (const float*)d_in[11];
  const float* db    = (const float*)d_in[12];
  const float* W1    = (const float*)d_in[13];
  const float* W2    = (const float*)d_in[14];
  float* out = (float*)d_out;   // f32 output

  float* ws = (float*)d_ws;
  size_t o = 0;
  float* x_in   = ws + o; o += (size_t)2048*512;    // emb; later: zt
  float* xg     = ws + o; o += (size_t)2048*4096;   // xg; later: hctx + partials
  float* x1     = ws + o; o += (size_t)2048*1024;   // layer-1 input; later: Hall
  float* encout = ws + o; o += (size_t)2048*1024;
  float* hA     = ws + o; o += 2*32*512;
  float* hB     = ws + o; o += 2*32*512;
  float* cbuf   = ws + o; o += 2*32*512;
  float* dh0    = ws + o; o += 32*1024;
  float* dc     = ws + o; o += 32*1024;
  float* nll    = ws + o; o += 2048;
  unsigned* cnt = (unsigned*)(ws + o); o += 64;     // 3 barrier counters
  float* Hall   = x1;                        // [64][32][1024]
  float* hctx   = xg;                        // [2048][2048]
  float* zt     = x_in;                      // [2048][512]
  float* Pmax   = xg + (size_t)4*1024*1024;             // [2048][125]
  int*   Parg   = (int*)(Pmax + (size_t)2048*NTILE);    // [2048][125]
  float* Psum   = Pmax + (size_t)2*2048*NTILE;          // [2048][125]
  float* Ltgt   = Pmax + (size_t)3*2048*NTILE;          // [2048]

  hipMemsetAsync(cnt, 0, 64*sizeof(unsigned), stream);

  // ---- encoder layer 0 (persistent) ----
  hipMemsetAsync(hA,   0, 2*32*512*sizeof(float), stream);
  hipMemsetAsync(cbuf, 0, 2*32*512*sizeof(float), stream);
  k_gather<<<dim3(2048), dim3(128), 0, stream>>>(semb, src, x_in, TSRC);
  launch_big(stream, x_in, 512, e0Wih, 512, e0b, xg, 4096, 2048, 4096, 512, 0);
  k_enc_layer<<<dim3(256), dim3(256), 0, stream>>>(e0Whh, xg, hA, hB, cbuf,
                                                   x1, 0, cnt);
  k_pack<<<dim3(128), dim3(256), 0, stream>>>(hA, cbuf, dh0, dc);

  // ---- encoder layer 1 (persistent) ----
  hipMemsetAsync(hA,   0, 2*32*512*sizeof(float), stream);
  hipMemsetAsync(cbuf, 0, 2*32*512*sizeof(float), stream);
  launch_big(stream, x1, 1024, e1Wih, 1024, e1b, xg, 4096, 2048, 4096, 1024, 0);
  k_enc_layer<<<dim3(256), dim3(256), 0, stream>>>(e1Whh, xg, hA, hB, cbuf,
                                                   encout, 1, cnt + 16);

  // ---- decoder phase A (persistent) ----
  k_gather<<<dim3(2048), dim3(128), 0, stream>>>(temb, trg, x_in, TTRG);
  launch_big(stream, x_in, 512, dWih, 512, db, xg, 4096, 2048, 4096, 512, 0);
  k_dec_layer<<<dim3(256), dim3(256), 0, stream>>>(dWhh, xg, dh0, dc, Hall, trg,
                                                   cnt + 32);

  // ---- decoder phase B: batched attention + projections + fused logits ----
  k_attn<<<dim3(2048), dim3(256), 0, stream>>>(Hall, encout, src, hctx);
  launch_med(stream, hctx, 2048, W1, 2048, nullptr, zt, 512, 2048, 512, 2048, 1);
  k_logits<<<dim3(16*NTILE), dim3(256), 0, stream>>>(zt, W2, trg, Pmax, Parg, Psum, Ltgt);
  k_combine<<<dim3(2048), dim3(128), 0, stream>>>(Pmax, Parg, Psum, Ltgt, trg, nll, out);
  k_final<<<dim3(1), dim3(256), 0, stream>>>(nll, trg, out);
}

// Round 12
// 4627.901 us; speedup vs baseline: 2.1006x; 2.1006x over previous
//
#include <hip/hip_runtime.h>
#include <hip/hip_bf16.h>
#include <math.h>

// Problem constants (B=32, Ts=64, Tt=66, E=H=512, V=16000)
#define TSRC 64
#define TTRG 66
#define NVOC 15996   // V-4
#define NTILE 125    // ceil(15996/128)

__device__ __forceinline__ float sigm(float x){ return 1.f/(1.f+expf(-x)); }

// ---------------------------------------------------------------------------
// Tiled GEMM: C = A[M,K] * B[N,K]^T (+bias, optional tanh epilogue).
// ---------------------------------------------------------------------------
struct GArgs {
  const float* A;  int lda;
  const float* Bw; int ldb;
  const float* bias;
  float* C; int ldc;
  int N; int K; int nNb; int act;
};

template<int BM,int BN,int BK,int TM,int TN>
__global__ __launch_bounds__(256)
void k_gemm(GArgs a)
{
  const int tid = threadIdx.x;
  const int mb = blockIdx.x / a.nNb;
  const int nb = blockIdx.x % a.nNb;
  const int m0 = mb*BM, n0 = nb*BN;
  const float* A  = a.A + (size_t)m0*a.lda;
  const float* Bw = a.Bw;

  __shared__ float As[BK][BM+1];
  __shared__ float Bs[BK][BN+4];
  const int tx = tid % (BN/TN);
  const int ty = tid / (BN/TN);
  float acc[TM][TN];
  #pragma unroll
  for (int i=0;i<TM;i++)
    #pragma unroll
    for (int j=0;j<TN;j++) acc[i][j]=0.f;

  for (int kt=0; kt<a.K; kt+=BK) {
    #pragma unroll
    for (int i=tid; i<BM*BK; i+=256) {
      int m = i/BK, k = i%BK;
      As[k][m] = A[(size_t)m*a.lda + kt + k];
    }
    #pragma unroll
    for (int i=tid; i<BN*BK; i+=256) {
      int n = i/BK, k = i%BK;
      int gn = n0+n;
      Bs[k][n] = (gn < a.N) ? Bw[(size_t)gn*a.ldb + kt + k] : 0.f;
    }
    __syncthreads();
    #pragma unroll
    for (int k=0;k<BK;k++) {
      float av[TM], bv[TN];
      #pragma unroll
      for (int i=0;i<TM;i++) av[i]=As[k][ty*TM+i];
      #pragma unroll
      for (int j=0;j<TN;j++) bv[j]=Bs[k][tx*TN+j];
      #pragma unroll
      for (int i=0;i<TM;i++)
        #pragma unroll
        for (int j=0;j<TN;j++)
          acc[i][j] = fmaf(av[i], bv[j], acc[i][j]);
    }
    __syncthreads();
  }
  #pragma unroll
  for (int i=0;i<TM;i++) {
    int m = m0 + ty*TM + i;
    #pragma unroll
    for (int j=0;j<TN;j++) {
      int n = n0 + tx*TN + j;
      if (n < a.N) {
        float v = acc[i][j];
        if (a.bias) v += a.bias[n];
        if (a.act)  v = tanhf(v);
        a.C[(size_t)m*a.ldc + n] = v;
      }
    }
  }
}

// ---------------------------------------------------------------------------
// Fused logits GEMM + per-tile row reduction (never materializes logits).
// XCD-swizzled: grid 2048; all 16 row-blocks sharing a W2 column tile land on
// the same XCD (bid mod 8 == nb mod 8) so each W2 tile lives in ONE L2.
// ---------------------------------------------------------------------------
__global__ __launch_bounds__(256)
void k_logits(const float* __restrict__ A, const float* __restrict__ Bw,
              const int* __restrict__ trg,
              float* __restrict__ Pmax, int* __restrict__ Parg,
              float* __restrict__ Psum, float* __restrict__ Ltgt)
{
  const int tid = threadIdx.x;
  const int j8   = blockIdx.x & 7;
  const int mb   = (blockIdx.x >> 3) & 15;
  const int nb   = ((blockIdx.x >> 7) << 3) + j8;
  if (nb >= NTILE) return;
  const int m0 = mb*128, n0 = nb*128;

  __shared__ float As[16][129];
  __shared__ float Bs[16][132];
  const int tx = tid & 15;
  const int ty = tid >> 4;
  float acc[8][8];
  #pragma unroll
  for (int i=0;i<8;i++)
    #pragma unroll
    for (int j=0;j<8;j++) acc[i][j]=0.f;

  for (int kt=0; kt<512; kt+=16) {
    #pragma unroll
    for (int i=tid; i<128*16; i+=256) {
      int m = i>>4, k = i&15;
      As[k][m] = A[(size_t)(m0+m)*512 + kt + k];
    }
    #pragma unroll
    for (int i=tid; i<128*16; i+=256) {
      int n = i>>4, k = i&15;
      int gn = n0+n;
      Bs[k][n] = (gn < NVOC) ? Bw[(size_t)gn*512 + kt + k] : 0.f;
    }
    __syncthreads();
    #pragma unroll
    for (int k=0;k<16;k++) {
      float av[8], bv[8];
      #pragma unroll
      for (int i=0;i<8;i++) av[i]=As[k][ty*8+i];
      #pragma unroll
      for (int j=0;j<8;j++) bv[j]=Bs[k][tx*8+j];
      #pragma unroll
      for (int i=0;i<8;i++)
        #pragma unroll
        for (int j=0;j<8;j++)
          acc[i][j] = fmaf(av[i], bv[j], acc[i][j]);
    }
    __syncthreads();
  }

  #pragma unroll
  for (int i=0;i<8;i++) {
    int r = m0 + ty*8 + i;                 // global row (= step*32 + b)
    int step = r >> 5, b = r & 31;
    int tgt = trg[b*TTRG + step + 1];
    int ti = tgt - 4;
    float m = -3.4e38f; int am = 0x7fffffff;
    #pragma unroll
    for (int j=0;j<8;j++) {
      int gn = n0 + tx*8 + j;
      if (gn < NVOC) {
        float x = acc[i][j];
        if (x > m || (x == m && gn < am)) { m = x; am = gn; }
      }
    }
    float s = 0.f;
    float lt = 0.f;
    #pragma unroll
    for (int j=0;j<8;j++) {
      int gn = n0 + tx*8 + j;
      if (gn < NVOC) {
        s += expf(acc[i][j] - m);
        if (gn == ti) lt = acc[i][j];
      }
    }
    #pragma unroll
    for (int d=1; d<16; d<<=1) {
      float m2 = __shfl_xor(m, d);
      int   a2 = __shfl_xor(am, d);
      float s2 = __shfl_xor(s, d);
      float l2 = __shfl_xor(lt, d);
      float M = fmaxf(m, m2);
      s = s*expf(m - M) + s2*expf(m2 - M);
      if (m2 > m || (m2 == m && a2 < am)) am = a2;
      m = M;
      lt += l2;
    }
    if (tx == 0) {
      size_t pi = (size_t)r*NTILE + nb;
      Pmax[pi] = m; Parg[pi] = am; Psum[pi] = s;
      if (ti >= n0 && ti < n0 + 128) Ltgt[r] = lt;
    }
  }
}

// Combine per-tile partials -> nll + pred per row.
__global__ __launch_bounds__(128)
void k_combine(const float* __restrict__ Pmax, const int* __restrict__ Parg,
               const float* __restrict__ Psum, const float* __restrict__ Ltgt,
               const int* __restrict__ trg,
               float* __restrict__ nll, float* __restrict__ outp)
{
  int r = blockIdx.x;
  int step = r >> 5, b = r & 31;
  int tid = threadIdx.x;
  __shared__ float sm[128]; __shared__ int sa[128]; __shared__ float ssum[128];
  float m = -3.4e38f; int am = 0x7fffffff; float s = 0.f;
  if (tid < NTILE) {
    size_t pi = (size_t)r*NTILE + tid;
    m = Pmax[pi]; am = Parg[pi]; s = Psum[pi];
  }
  sm[tid]=m; sa[tid]=am; ssum[tid]=s; __syncthreads();
  for (int off=64; off; off>>=1) {
    if (tid < off) {
      float m2 = sm[tid+off]; int a2 = sa[tid+off]; float s2 = ssum[tid+off];
      float m1 = sm[tid];     int a1 = sa[tid];     float s1 = ssum[tid];
      float M = fmaxf(m1, m2);
      ssum[tid] = s1*expf(m1 - M) + s2*expf(m2 - M);
      if (m2 > m1 || (m2 == m1 && a2 < a1)) sa[tid] = a2;
      sm[tid] = M;
    }
    __syncthreads();
  }
  if (tid == 0) {
    int tgt = trg[b*TTRG + step + 1];
    float nl = 0.f;
    if (tgt != 0) nl = -(Ltgt[r] - sm[0] - logf(ssum[0]));
    nll[step*32 + b] = nl;
    outp[1 + b*64 + step] = (float)(sa[0] + 4);
  }
}

// Embedding gather
__global__ void k_gather(const float* __restrict__ emb, const int* __restrict__ tok,
                         float* __restrict__ outp, int Tfull)
{
  int r = blockIdx.x;
  int t = r >> 5, b = r & 31;
  int token = tok[b*Tfull + t];
  const float4* s = (const float4*)(emb + (size_t)token*512);
  float4* d = (float4*)(outp + (size_t)r*512);
  d[threadIdx.x] = s[threadIdx.x];
}

// ---------------------------------------------------------------------------
// Encoder recurrent GEMM, K-split partials.
// grid 128: ks(4) x dir(2) x jt(16). P layout: [(ks*2+dir)*32 + b][2048].
// ---------------------------------------------------------------------------
__global__ __launch_bounds__(256)
void k_rgemm_enc(const float* __restrict__ Whh,   // [2][2048][512]
                 const float* __restrict__ hin,   // [2*32][512]
                 float* __restrict__ P)
{
  const int ks  = blockIdx.x >> 5;
  const int rem = blockIdx.x & 31;
  const int dir = rem >> 4;
  const int jt  = rem & 15;
  const int j0  = jt*32;
  const int tid = threadIdx.x;
  const int jcol = tid & 31;
  const int bq   = tid >> 5;
  __shared__ float ws[128][65];
  __shared__ float hs[64][36];
  const float* W = Whh + (size_t)dir*2048*512;
  const float* H = hin + (size_t)dir*32*512;
  float acc[4][4];
  #pragma unroll
  for (int g=0;g<4;g++)
    #pragma unroll
    for (int i=0;i<4;i++) acc[g][i]=0.f;

  for (int kt=ks*128; kt<ks*128+128; kt+=64) {
    for (int idx=tid; idx<128*64; idx+=256) {
      int r = idx >> 6, k = idx & 63;
      int gate = r >> 5, jc = r & 31;
      ws[r][k] = W[(size_t)(gate*512 + j0 + jc)*512 + kt + k];
    }
    for (int idx=tid; idx<32*64; idx+=256) {
      int b = idx >> 6, k = idx & 63;
      hs[k][b] = H[(size_t)b*512 + kt + k];
    }
    __syncthreads();
    #pragma unroll 8
    for (int k=0;k<64;k++) {
      float4 hv = *reinterpret_cast<const float4*>(&hs[k][bq*4]);
      #pragma unroll
      for (int g=0;g<4;g++) {
        float wv = ws[g*32+jcol][k];
        acc[g][0] = fmaf(hv.x, wv, acc[g][0]);
        acc[g][1] = fmaf(hv.y, wv, acc[g][1]);
        acc[g][2] = fmaf(hv.z, wv, acc[g][2]);
        acc[g][3] = fmaf(hv.w, wv, acc[g][3]);
      }
    }
    __syncthreads();
  }
  #pragma unroll
  for (int g=0;g<4;g++)
    #pragma unroll
    for (int i=0;i<4;i++)
      P[((size_t)(ks*2+dir)*32 + bq*4+i)*2048 + g*512 + j0 + jcol] = acc[g][i];
}

// Encoder combine: sum 4 K-chunks + xg, LSTM update, scatter.
__global__ __launch_bounds__(256)
void k_enc_combine(const float* __restrict__ P, const float* __restrict__ xg,
                   float* __restrict__ cst, float* __restrict__ hout,
                   float* __restrict__ xout, int tf, int tb, int mode)
{
  int t = blockIdx.x*256 + threadIdx.x;   // 32768
  int jh = t & 511, b = (t>>9)&31, dir = t>>14;
  int tt = dir ? tb : tf;
  const float* x = xg + ((size_t)tt*32 + b)*4096 + dir*2048;
  float g4[4];
  #pragma unroll
  for (int g=0; g<4; g++) {
    float s = 0.f;
    #pragma unroll
    for (int ks=0; ks<4; ks++)
      s += P[((size_t)(ks*2+dir)*32 + b)*2048 + g*512 + jh];
    g4[g] = s + x[g*512 + jh];
  }
  size_t ci = ((size_t)dir*32 + b)*512 + jh;
  float cn = sigm(g4[1])*cst[ci] + sigm(g4[0])*tanhf(g4[2]);
  float hn = sigm(g4[3])*tanhf(cn);
  cst[ci] = cn;
  hout[ci] = hn;
  if (mode == 0) xout[((size_t)tt*32 + b)*1024 + dir*512 + jh] = hn;  // x1
  else           xout[((size_t)b*64 + tt)*1024 + dir*512 + jh] = hn;  // enc_out
}

// Pack layer-0 final states into decoder initial h/c
__global__ void k_pack(const float* __restrict__ hfin, const float* __restrict__ cfin,
                       float* __restrict__ dh, float* __restrict__ dcc)
{
  int tid = blockIdx.x*256 + threadIdx.x;   // 32768
  int j = tid & 1023, b = tid >> 10;
  int dir = j >> 9, jj = j & 511;
  size_t si = ((size_t)dir*32 + b)*512 + jj;
  dh[(size_t)b*1024 + j]  = hfin[si];
  dcc[(size_t)b*1024 + j] = cfin[si];
}

// ---------------------------------------------------------------------------
// Decoder recurrent GEMM, K-split partials.
// grid 256: ks(8) x jt(32). P layout: [ks*32 + b][4096].
// ---------------------------------------------------------------------------
__global__ __launch_bounds__(256)
void k_rgemm_dec(const float* __restrict__ Whh,   // [4096][1024]
                 const float* __restrict__ hin,   // [32][1024]
                 float* __restrict__ P)
{
  const int ks = blockIdx.x >> 5;
  const int jt = blockIdx.x & 31;
  const int j0 = jt*32;
  const int tid = threadIdx.x;
  const int jcol = tid & 31;
  const int bq   = tid >> 5;
  __shared__ float ws[128][65];
  __shared__ float hs[64][36];
  float acc[4][4];
  #pragma unroll
  for (int g=0;g<4;g++)
    #pragma unroll
    for (int i=0;i<4;i++) acc[g][i]=0.f;

  for (int kt=ks*128; kt<ks*128+128; kt+=64) {
    for (int idx=tid; idx<128*64; idx+=256) {
      int r = idx >> 6, k = idx & 63;
      int gate = r >> 5, jc = r & 31;
      ws[r][k] = Whh[(size_t)(gate*1024 + j0 + jc)*1024 + kt + k];
    }
    for (int idx=tid; idx<32*64; idx+=256) {
      int b = idx >> 6, k = idx & 63;
      hs[k][b] = hin[(size_t)b*1024 + kt + k];
    }
    __syncthreads();
    #pragma unroll 8
    for (int k=0;k<64;k++) {
      float4 hv = *reinterpret_cast<const float4*>(&hs[k][bq*4]);
      #pragma unroll
      for (int g=0;g<4;g++) {
        float wv = ws[g*32+jcol][k];
        acc[g][0] = fmaf(hv.x, wv, acc[g][0]);
        acc[g][1] = fmaf(hv.y, wv, acc[g][1]);
        acc[g][2] = fmaf(hv.z, wv, acc[g][2]);
        acc[g][3] = fmaf(hv.w, wv, acc[g][3]);
      }
    }
    __syncthreads();
  }
  #pragma unroll
  for (int g=0;g<4;g++)
    #pragma unroll
    for (int i=0;i<4;i++)
      P[((size_t)ks*32 + bq*4+i)*4096 + g*1024 + j0 + jcol] = acc[g][i];
}

// Decoder combine: sum 8 K-chunks + xg, LSTM update + PAD mask -> Hall[t].
__global__ __launch_bounds__(256)
void k_dec_combine(const float* __restrict__ P, const float* __restrict__ xg_t,
                   float* __restrict__ cst, float* __restrict__ hall_t,
                   const int* __restrict__ trg, int step)
{
  int t = blockIdx.x*256 + threadIdx.x;   // 32768
  int jh = t & 1023, b = t >> 10;
  int tgt = trg[b*TTRG + step + 1];
  bool dm = (tgt == 0);
  const float* x = xg_t + (size_t)b*4096;
  float g4[4];
  #pragma unroll
  for (int g=0; g<4; g++) {
    float s = 0.f;
    #pragma unroll
    for (int ks=0; ks<8; ks++)
      s += P[((size_t)ks*32 + b)*4096 + g*1024 + jh];
    g4[g] = s + x[g*1024 + jh];
  }
  size_t ci = (size_t)b*1024 + jh;
  float cn = sigm(g4[1])*cst[ci] + sigm(g4[0])*tanhf(g4[2]);
  float hn = sigm(g4[3])*tanhf(cn);
  cst[ci] = cn;                    // cell NOT masked (matches reference)
  hall_t[ci] = dm ? 0.f : hn;      // h masked
}

// ---------------------------------------------------------------------------
// Batched attention (phase B)
// ---------------------------------------------------------------------------
__global__ __launch_bounds__(256)
void k_attn(const float* __restrict__ Hall,    // [64][32][1024]
            const float* __restrict__ encout,  // [32][64][1024]
            const int* __restrict__ src,
            float* __restrict__ hctx)          // [2048][2048]
{
  int bid = blockIdx.x;
  int t = bid >> 5, b = bid & 31;
  int tid = threadIdx.x;
  __shared__ float sh[1024];
  __shared__ float ssc[64];
  const float* h = Hall + ((size_t)t*32 + b)*1024;
  size_t row = (size_t)t*32 + b;
  #pragma unroll
  for (int r=0;r<4;r++) {
    int jh = tid + 256*r;
    float v = h[jh];
    sh[jh] = v;
    hctx[row*2048 + jh] = v;
  }
  __syncthreads();
  {
    int tq = tid >> 2, part = tid & 3;
    const float* eo = encout + ((size_t)b*64 + tq)*1024 + part*256;
    const float* hh = sh + part*256;
    float s = 0.f;
    for (int k=0;k<256;k++) s = fmaf(hh[k], eo[k], s);
    s += __shfl_xor(s, 1);
    s += __shfl_xor(s, 2);
    if (part == 0) ssc[tq] = (src[b*TSRC + tq] == 0) ? -1e9f : s;
  }
  __syncthreads();
  if (tid < 64) {
    float v = ssc[tid];
    float m = v;
    for (int d=1; d<64; d<<=1) m = fmaxf(m, __shfl_xor(m, d));
    float e = expf(v - m);
    float su = e;
    for (int d=1; d<64; d<<=1) su += __shfl_xor(su, d);
    ssc[tid] = e / su;
  }
  __syncthreads();
  #pragma unroll
  for (int r=0;r<4;r++) {
    int k = tid + 256*r;
    float a = 0.f;
    const float* eb = encout + (size_t)b*65536 + k;
    for (int tt=0;tt<64;tt++) a = fmaf(ssc[tt], eb[tt*1024], a);
    hctx[row*2048 + 1024 + k] = a;
  }
}

// Final: loss = sum(nll)/denom
__global__ __launch_bounds__(256)
void k_final(const float* __restrict__ nll, const int* __restrict__ trg,
             float* __restrict__ outp)
{
  int tid = threadIdx.x;
  __shared__ float ss[256]; __shared__ int sc[256];
  float s = 0.f; int cnt = 0;
  for (int i=tid; i<2048; i+=256) {
    s += nll[i];
    int b = i >> 6, t = (i & 63) + 1;
    cnt += (trg[b*TTRG + t] != 0);
  }
  ss[tid]=s; sc[tid]=cnt; __syncthreads();
  for (int off=128; off; off>>=1) {
    if (tid<off) { ss[tid]+=ss[tid+off]; sc[tid]+=sc[tid+off]; }
    __syncthreads();
  }
  if (tid==0) outp[0] = ss[0] / (float)sc[0];
}

// ---------------------------------------------------------------------------
static void launch_big(hipStream_t st, const float* A, int lda,
                       const float* Bw, int ldb, const float* bias,
                       float* C, int ldc, int M, int N, int K, int act)
{
  GArgs a;
  a.A=A; a.lda=lda;
  a.Bw=Bw; a.ldb=ldb;
  a.bias=bias;
  a.C=C; a.ldc=ldc;
  a.N=N; a.K=K; a.nNb=(N+127)/128; a.act=act;
  dim3 g((M/128)*a.nNb, 1, 1);
  k_gemm<128,128,16,8,8><<<g, dim3(256), 0, st>>>(a);
}

static void launch_med(hipStream_t st, const float* A, int lda,
                       const float* Bw, int ldb, const float* bias,
                       float* C, int ldc, int M, int N, int K, int act)
{
  GArgs a;
  a.A=A; a.lda=lda;
  a.Bw=Bw; a.ldb=ldb;
  a.bias=bias;
  a.C=C; a.ldc=ldc;
  a.N=N; a.K=K; a.nNb=(N+63)/64; a.act=act;
  dim3 g((M/64)*a.nNb, 1, 1);
  k_gemm<64,64,16,4,4><<<g, dim3(256), 0, st>>>(a);
}

extern "C" void kernel_launch(void* const* d_in, const int* in_sizes, int n_in,
                              void* d_out, int out_size, void* d_ws, size_t ws_size,
                              hipStream_t stream)
{
  (void)in_sizes; (void)n_in; (void)out_size; (void)ws_size;
  const int*   src   = (const int*)  d_in[0];
  const int*   trg   = (const int*)  d_in[1];
  const float* semb  = (const float*)d_in[2];
  const float* temb  = (const float*)d_in[3];
  const float* e0Wih = (const float*)d_in[4];
  const float* e0Whh = (const float*)d_in[5];
  const float* e0b   = (const float*)d_in[6];
  const float* e1Wih = (const float*)d_in[7];
  const float* e1Whh = (const float*)d_in[8];
  const float* e1b   = (const float*)d_in[9];
  const float* dWih  = (const float*)d_in[10];
  const float* dWhh  = (const float*)d_in[11];
  const float* db    = (const float*)d_in[12];
  const float* W1    = (const float*)d_in[13];
  const float* W2    = (const float*)d_in[14];
  float* out = (float*)d_out;   // f32 output

  float* ws = (float*)d_ws;
  size_t o = 0;
  float* x_in   = ws + o; o += (size_t)2048*512;    // emb; later: zt
  float* xg     = ws + o; o += (size_t)2048*4096;   // xg; later: hctx + partials
  float* x1     = ws + o; o += (size_t)2048*1024;   // layer-1 input; later: Hall
  float* encout = ws + o; o += (size_t)2048*1024;
  float* hA     = ws + o; o += 2*32*512;
  float* hB     = ws + o; o += 2*32*512;
  float* cbuf   = ws + o; o += 2*32*512;
  float* dh0    = ws + o; o += 32*1024;
  float* dc     = ws + o; o += 32*1024;
  float* nll    = ws + o; o += 2048;
  float* P      = ws + o; o += (size_t)8*32*4096;   // K-split partials (4 MB)
  float* Hall   = x1;                        // [64][32][1024]
  float* hctx   = xg;                        // [2048][2048]
  float* zt     = x_in;                      // [2048][512]
  float* Pmax   = xg + (size_t)4*1024*1024;             // [2048][125]
  int*   Parg   = (int*)(Pmax + (size_t)2048*NTILE);    // [2048][125]
  float* Psum   = Pmax + (size_t)2*2048*NTILE;          // [2048][125]
  float* Ltgt   = Pmax + (size_t)3*2048*NTILE;          // [2048]

  // ---- encoder layer 0 ----
  hipMemsetAsync(hA,   0, 2*32*512*sizeof(float), stream);
  hipMemsetAsync(cbuf, 0, 2*32*512*sizeof(float), stream);
  k_gather<<<dim3(2048), dim3(128), 0, stream>>>(semb, src, x_in, TSRC);
  launch_big(stream, x_in, 512, e0Wih, 512, e0b, xg, 4096, 2048, 4096, 512, 0);
  for (int s=0; s<64; s++) {
    float* hin  = (s&1) ? hB : hA;
    float* hout = (s&1) ? hA : hB;
    k_rgemm_enc<<<dim3(128), dim3(256), 0, stream>>>(e0Whh, hin, P);
    k_enc_combine<<<dim3(128), dim3(256), 0, stream>>>(P, xg, cbuf, hout, x1, s, 63-s, 0);
  }
  k_pack<<<dim3(128), dim3(256), 0, stream>>>(hA, cbuf, dh0, dc);

  // ---- encoder layer 1 ----
  hipMemsetAsync(hA,   0, 2*32*512*sizeof(float), stream);
  hipMemsetAsync(cbuf, 0, 2*32*512*sizeof(float), stream);
  launch_big(stream, x1, 1024, e1Wih, 1024, e1b, xg, 4096, 2048, 4096, 1024, 0);
  for (int s=0; s<64; s++) {
    float* hin  = (s&1) ? hB : hA;
    float* hout = (s&1) ? hA : hB;
    k_rgemm_enc<<<dim3(128), dim3(256), 0, stream>>>(e1Whh, hin, P);
    k_enc_combine<<<dim3(128), dim3(256), 0, stream>>>(P, xg, cbuf, hout, encout, s, 63-s, 1);
  }

  // ---- decoder phase A: sequential recurrence into Hall ----
  k_gather<<<dim3(2048), dim3(128), 0, stream>>>(temb, trg, x_in, TTRG);
  launch_big(stream, x_in, 512, dWih, 512, db, xg, 4096, 2048, 4096, 512, 0);
  for (int st=0; st<64; st++) {
    const float* hin = (st == 0) ? dh0 : (Hall + (size_t)(st-1)*32*1024);
    k_rgemm_dec<<<dim3(256), dim3(256), 0, stream>>>(dWhh, hin, P);
    k_dec_combine<<<dim3(128), dim3(256), 0, stream>>>(P, xg + (size_t)st*32*4096,
                 dc, Hall + (size_t)st*32*1024, trg, st);
  }

  // ---- decoder phase B: batched attention + projections + fused logits ----
  k_attn<<<dim3(2048), dim3(256), 0, stream>>>(Hall, encout, src, hctx);
  launch_med(stream, hctx, 2048, W1, 2048, nullptr, zt, 512, 2048, 512, 2048, 1);
  k_logits<<<dim3(2048), dim3(256), 0, stream>>>(zt, W2, trg, Pmax, Parg, Psum, Ltgt);
  k_combine<<<dim3(2048), dim3(128), 0, stream>>>(Pmax, Parg, Psum, Ltgt, trg, nll, out);
  k_final<<<dim3(1), dim3(256), 0, stream>>>(nll, trg, out);
}

// Round 13
// 4260.762 us; speedup vs baseline: 2.2816x; 1.0862x over previous
//
#include <hip/hip_runtime.h>
#include <hip/hip_bf16.h>
#include <math.h>

// Problem constants (B=32, Ts=64, Tt=66, E=H=512, V=16000)
#define TSRC 64
#define TTRG 66
#define NVOC 15996   // V-4
#define NTILE 125    // ceil(15996/128)

__device__ __forceinline__ float sigm(float x){ return 1.f/(1.f+expf(-x)); }

// ---------------------------------------------------------------------------
// Tiled GEMM: C = A[M,K] * B[N,K]^T (+bias, optional tanh epilogue).
// ---------------------------------------------------------------------------
struct GArgs {
  const float* A;  int lda;
  const float* Bw; int ldb;
  const float* bias;
  float* C; int ldc;
  int N; int K; int nNb; int act;
};

template<int BM,int BN,int BK,int TM,int TN>
__global__ __launch_bounds__(256)
void k_gemm(GArgs a)
{
  const int tid = threadIdx.x;
  const int mb = blockIdx.x / a.nNb;
  const int nb = blockIdx.x % a.nNb;
  const int m0 = mb*BM, n0 = nb*BN;
  const float* A  = a.A + (size_t)m0*a.lda;
  const float* Bw = a.Bw;

  __shared__ float As[BK][BM+1];
  __shared__ float Bs[BK][BN+4];
  const int tx = tid % (BN/TN);
  const int ty = tid / (BN/TN);
  float acc[TM][TN];
  #pragma unroll
  for (int i=0;i<TM;i++)
    #pragma unroll
    for (int j=0;j<TN;j++) acc[i][j]=0.f;

  for (int kt=0; kt<a.K; kt+=BK) {
    #pragma unroll
    for (int i=tid; i<BM*BK; i+=256) {
      int m = i/BK, k = i%BK;
      As[k][m] = A[(size_t)m*a.lda + kt + k];
    }
    #pragma unroll
    for (int i=tid; i<BN*BK; i+=256) {
      int n = i/BK, k = i%BK;
      int gn = n0+n;
      Bs[k][n] = (gn < a.N) ? Bw[(size_t)gn*a.ldb + kt + k] : 0.f;
    }
    __syncthreads();
    #pragma unroll
    for (int k=0;k<BK;k++) {
      float av[TM], bv[TN];
      #pragma unroll
      for (int i=0;i<TM;i++) av[i]=As[k][ty*TM+i];
      #pragma unroll
      for (int j=0;j<TN;j++) bv[j]=Bs[k][tx*TN+j];
      #pragma unroll
      for (int i=0;i<TM;i++)
        #pragma unroll
        for (int j=0;j<TN;j++)
          acc[i][j] = fmaf(av[i], bv[j], acc[i][j]);
    }
    __syncthreads();
  }
  #pragma unroll
  for (int i=0;i<TM;i++) {
    int m = m0 + ty*TM + i;
    #pragma unroll
    for (int j=0;j<TN;j++) {
      int n = n0 + tx*TN + j;
      if (n < a.N) {
        float v = acc[i][j];
        if (a.bias) v += a.bias[n];
        if (a.act)  v = tanhf(v);
        a.C[(size_t)m*a.ldc + n] = v;
      }
    }
  }
}

// ---------------------------------------------------------------------------
// Fused logits GEMM + per-tile row reduction (never materializes logits).
// XCD-swizzled: all 16 row-blocks sharing a W2 tile land on one XCD.
// ---------------------------------------------------------------------------
__global__ __launch_bounds__(256)
void k_logits(const float* __restrict__ A, const float* __restrict__ Bw,
              const int* __restrict__ trg,
              float* __restrict__ Pmax, int* __restrict__ Parg,
              float* __restrict__ Psum, float* __restrict__ Ltgt)
{
  const int tid = threadIdx.x;
  const int j8   = blockIdx.x & 7;
  const int mb   = (blockIdx.x >> 3) & 15;
  const int nb   = ((blockIdx.x >> 7) << 3) + j8;
  if (nb >= NTILE) return;
  const int m0 = mb*128, n0 = nb*128;

  __shared__ float As[16][129];
  __shared__ float Bs[16][132];
  const int tx = tid & 15;
  const int ty = tid >> 4;
  float acc[8][8];
  #pragma unroll
  for (int i=0;i<8;i++)
    #pragma unroll
    for (int j=0;j<8;j++) acc[i][j]=0.f;

  for (int kt=0; kt<512; kt+=16) {
    #pragma unroll
    for (int i=tid; i<128*16; i+=256) {
      int m = i>>4, k = i&15;
      As[k][m] = A[(size_t)(m0+m)*512 + kt + k];
    }
    #pragma unroll
    for (int i=tid; i<128*16; i+=256) {
      int n = i>>4, k = i&15;
      int gn = n0+n;
      Bs[k][n] = (gn < NVOC) ? Bw[(size_t)gn*512 + kt + k] : 0.f;
    }
    __syncthreads();
    #pragma unroll
    for (int k=0;k<16;k++) {
      float av[8], bv[8];
      #pragma unroll
      for (int i=0;i<8;i++) av[i]=As[k][ty*8+i];
      #pragma unroll
      for (int j=0;j<8;j++) bv[j]=Bs[k][tx*8+j];
      #pragma unroll
      for (int i=0;i<8;i++)
        #pragma unroll
        for (int j=0;j<8;j++)
          acc[i][j] = fmaf(av[i], bv[j], acc[i][j]);
    }
    __syncthreads();
  }

  #pragma unroll
  for (int i=0;i<8;i++) {
    int r = m0 + ty*8 + i;                 // global row (= step*32 + b)
    int step = r >> 5, b = r & 31;
    int tgt = trg[b*TTRG + step + 1];
    int ti = tgt - 4;
    float m = -3.4e38f; int am = 0x7fffffff;
    #pragma unroll
    for (int j=0;j<8;j++) {
      int gn = n0 + tx*8 + j;
      if (gn < NVOC) {
        float x = acc[i][j];
        if (x > m || (x == m && gn < am)) { m = x; am = gn; }
      }
    }
    float s = 0.f;
    float lt = 0.f;
    #pragma unroll
    for (int j=0;j<8;j++) {
      int gn = n0 + tx*8 + j;
      if (gn < NVOC) {
        s += expf(acc[i][j] - m);
        if (gn == ti) lt = acc[i][j];
      }
    }
    #pragma unroll
    for (int d=1; d<16; d<<=1) {
      float m2 = __shfl_xor(m, d);
      int   a2 = __shfl_xor(am, d);
      float s2 = __shfl_xor(s, d);
      float l2 = __shfl_xor(lt, d);
      float M = fmaxf(m, m2);
      s = s*expf(m - M) + s2*expf(m2 - M);
      if (m2 > m || (m2 == m && a2 < am)) am = a2;
      m = M;
      lt += l2;
    }
    if (tx == 0) {
      size_t pi = (size_t)r*NTILE + nb;
      Pmax[pi] = m; Parg[pi] = am; Psum[pi] = s;
      if (ti >= n0 && ti < n0 + 128) Ltgt[r] = lt;
    }
  }
}

// Combine per-tile partials -> nll + pred per row.
__global__ __launch_bounds__(128)
void k_combine(const float* __restrict__ Pmax, const int* __restrict__ Parg,
               const float* __restrict__ Psum, const float* __restrict__ Ltgt,
               const int* __restrict__ trg,
               float* __restrict__ nll, float* __restrict__ outp)
{
  int r = blockIdx.x;
  int step = r >> 5, b = r & 31;
  int tid = threadIdx.x;
  __shared__ float sm[128]; __shared__ int sa[128]; __shared__ float ssum[128];
  float m = -3.4e38f; int am = 0x7fffffff; float s = 0.f;
  if (tid < NTILE) {
    size_t pi = (size_t)r*NTILE + tid;
    m = Pmax[pi]; am = Parg[pi]; s = Psum[pi];
  }
  sm[tid]=m; sa[tid]=am; ssum[tid]=s; __syncthreads();
  for (int off=64; off; off>>=1) {
    if (tid < off) {
      float m2 = sm[tid+off]; int a2 = sa[tid+off]; float s2 = ssum[tid+off];
      float m1 = sm[tid];     int a1 = sa[tid];     float s1 = ssum[tid];
      float M = fmaxf(m1, m2);
      ssum[tid] = s1*expf(m1 - M) + s2*expf(m2 - M);
      if (m2 > m1 || (m2 == m1 && a2 < a1)) sa[tid] = a2;
      sm[tid] = M;
    }
    __syncthreads();
  }
  if (tid == 0) {
    int tgt = trg[b*TTRG + step + 1];
    float nl = 0.f;
    if (tgt != 0) nl = -(Ltgt[r] - sm[0] - logf(ssum[0]));
    nll[step*32 + b] = nl;
    outp[1 + b*64 + step] = (float)(sa[0] + 4);
  }
}

// Embedding gather
__global__ void k_gather(const float* __restrict__ emb, const int* __restrict__ tok,
                         float* __restrict__ outp, int Tfull)
{
  int r = blockIdx.x;
  int t = r >> 5, b = r & 31;
  int token = tok[b*Tfull + t];
  const float4* s = (const float4*)(emb + (size_t)token*512);
  float4* d = (float4*)(outp + (size_t)r*512);
  d[threadIdx.x] = s[threadIdx.x];
}

// ---------------------------------------------------------------------------
// FUSED encoder LSTM step (ONE launch): full-K gates + update + scatter.
// grid 256: bid = dir*128 + jb; block owns dir, hidden j0=jb*4..+3 (16 rows).
// Thread (kg=tid>>5 in [0,8), b=tid&31) holds h[b][kg*64..+63] in registers.
// w broadcast from LDS (4 FMA : 1 LDS-b128). In-wave kg-fold + LDS reduce.
// ---------------------------------------------------------------------------
__global__ __launch_bounds__(256)
void k_estep(const float* __restrict__ Whh,   // [2][2048][512]
             const float* __restrict__ xg,    // [2048][4096]
             const float* __restrict__ hin,   // [2*32][512]
             float* __restrict__ hout,        // [2*32][512]
             float* __restrict__ cst,         // [2*32][512]
             float* __restrict__ xout, int s, int mode)
{
  const int bid = blockIdx.x;
  const int dir = bid >> 7;
  const int j0  = (bid & 127) * 4;
  const int tid = threadIdx.x;
  const int kg  = tid >> 5;      // 0..7, k-slice of 64
  const int b   = tid & 31;
  __shared__ float4 wl4[16*128];         // 16 rows x 512 floats = 32 KB
  __shared__ float red[4*16*33];         // [wave][row][b(+pad)]

  // stage W slice (coalesced): row r=g*4+jj -> global row g*512 + j0 + jj
  {
    const float* W = Whh + (size_t)dir*2048*512;
    for (int idx = tid; idx < 16*128; idx += 256) {
      int r = idx >> 7, c = idx & 127;
      int g = r >> 2, jj = r & 3;
      wl4[idx] = ((const float4*)(W + (size_t)(g*512 + j0 + jj)*512))[c];
    }
  }
  // h slice into registers
  float4 hreg[16];
  {
    const float4* H4 = (const float4*)(hin + (size_t)dir*32*512);
    #pragma unroll
    for (int j=0;j<16;j++) hreg[j] = H4[(size_t)b*128 + kg*16 + j];
  }
  __syncthreads();

  float acc[16];
  #pragma unroll
  for (int r=0;r<16;r++) {
    const float4* wr = wl4 + r*128 + kg*16;
    float a0=0.f,a1=0.f,a2=0.f,a3=0.f;
    #pragma unroll
    for (int j=0;j<16;j++) {
      float4 w = wr[j];
      a0 = fmaf(w.x, hreg[j].x, a0);
      a1 = fmaf(w.y, hreg[j].y, a1);
      a2 = fmaf(w.z, hreg[j].z, a2);
      a3 = fmaf(w.w, hreg[j].w, a3);
    }
    acc[r] = (a0+a1)+(a2+a3);
  }
  // fold kg pairs within wave (lane ^ 32)
  #pragma unroll
  for (int r=0;r<16;r++) acc[r] += __shfl_xor(acc[r], 32);
  const int wv = tid >> 6;
  if ((tid & 32) == 0) {
    #pragma unroll
    for (int r=0;r<16;r++) red[wv*528 + r*33 + b] = acc[r];
  }
  __syncthreads();

  if (tid < 128) {
    int jj = tid >> 5, bb = tid & 31;
    int jh = j0 + jj;
    int t  = dir ? (63 - s) : s;
    const float* x = xg + ((size_t)t*32 + bb)*4096 + dir*2048;
    float g4[4];
    #pragma unroll
    for (int g=0; g<4; g++) {
      int r = g*4 + jj;
      g4[g] = ((red[0*528 + r*33 + bb] + red[1*528 + r*33 + bb])
             + (red[2*528 + r*33 + bb] + red[3*528 + r*33 + bb]))
             + x[g*512 + jh];
    }
    size_t ci = ((size_t)dir*32 + bb)*512 + jh;
    float cn = sigm(g4[1])*cst[ci] + sigm(g4[0])*tanhf(g4[2]);
    float hn = sigm(g4[3])*tanhf(cn);
    cst[ci] = cn;
    hout[ci] = hn;
    if (mode == 0) xout[((size_t)t*32 + bb)*1024 + dir*512 + jh] = hn;  // x1
    else           xout[((size_t)bb*64 + t)*1024 + dir*512 + jh] = hn;  // enc_out
  }
}

// ---------------------------------------------------------------------------
// FUSED decoder LSTM step (ONE launch): full-K gates + update + mask -> Hall.
// grid 256: block owns hidden j0=bid*4..+3 (16 gate-rows), K=1024.
// Thread (kg=tid>>5, b=tid&31) holds h[b][kg*128..+127] in registers.
// W staged in 2 halves of 8 rows (32 KB).
// ---------------------------------------------------------------------------
__global__ __launch_bounds__(256)
void k_dstep(const float* __restrict__ Whh,   // [4096][1024]
             const float* __restrict__ xg_t,  // [32][4096] this step
             const float* __restrict__ hin,   // [32][1024]
             float* __restrict__ cst,         // [32][1024]
             float* __restrict__ hall_t,      // [32][1024]
             const int* __restrict__ trg, int st)
{
  const int bid = blockIdx.x;
  const int j0  = bid*4;
  const int tid = threadIdx.x;
  const int kg  = tid >> 5;      // 0..7, k-slice of 128
  const int b   = tid & 31;
  __shared__ float4 wl4[8*256];          // 8 rows x 1024 floats = 32 KB
  __shared__ float red[4*16*33];

  float4 hreg[32];
  {
    const float4* H4 = (const float4*)hin;
    #pragma unroll
    for (int j=0;j<32;j++) hreg[j] = H4[(size_t)b*256 + kg*32 + j];
  }

  float acc[16];
  #pragma unroll
  for (int hh=0; hh<2; hh++) {
    // stage 8 rows: local rl -> global row g*1024 + j0 + jj, r = hh*8+rl
    for (int idx = tid; idx < 8*256; idx += 256) {
      int rl = idx >> 8, c = idx & 255;
      int r = hh*8 + rl;
      int g = r >> 2, jj = r & 3;
      wl4[idx] = ((const float4*)(Whh + (size_t)(g*1024 + j0 + jj)*1024))[c];
    }
    __syncthreads();
    #pragma unroll
    for (int rl=0; rl<8; rl++) {
      const float4* wr = wl4 + rl*256 + kg*32;
      float a0=0.f,a1=0.f,a2=0.f,a3=0.f;
      #pragma unroll
      for (int j=0;j<32;j++) {
        float4 w = wr[j];
        a0 = fmaf(w.x, hreg[j].x, a0);
        a1 = fmaf(w.y, hreg[j].y, a1);
        a2 = fmaf(w.z, hreg[j].z, a2);
        a3 = fmaf(w.w, hreg[j].w, a3);
      }
      acc[hh*8 + rl] = (a0+a1)+(a2+a3);
    }
    __syncthreads();
  }
  #pragma unroll
  for (int r=0;r<16;r++) acc[r] += __shfl_xor(acc[r], 32);
  const int wv = tid >> 6;
  if ((tid & 32) == 0) {
    #pragma unroll
    for (int r=0;r<16;r++) red[wv*528 + r*33 + b] = acc[r];
  }
  __syncthreads();

  if (tid < 128) {
    int jj = tid >> 5, bb = tid & 31;
    int jh = j0 + jj;
    int tgt = trg[bb*TTRG + st + 1];
    bool dm = (tgt == 0);
    const float* x = xg_t + (size_t)bb*4096;
    float g4[4];
    #pragma unroll
    for (int g=0; g<4; g++) {
      int r = g*4 + jj;
      g4[g] = ((red[0*528 + r*33 + bb] + red[1*528 + r*33 + bb])
             + (red[2*528 + r*33 + bb] + red[3*528 + r*33 + bb]))
             + x[g*1024 + jh];
    }
    size_t ci = (size_t)bb*1024 + jh;
    float cn = sigm(g4[1])*cst[ci] + sigm(g4[0])*tanhf(g4[2]);
    float hn = sigm(g4[3])*tanhf(cn);
    cst[ci] = cn;                    // cell NOT masked (matches reference)
    hall_t[ci] = dm ? 0.f : hn;      // h masked
  }
}

// Pack layer-0 final states into decoder initial h/c
__global__ void k_pack(const float* __restrict__ hfin, const float* __restrict__ cfin,
                       float* __restrict__ dh, float* __restrict__ dcc)
{
  int tid = blockIdx.x*256 + threadIdx.x;   // 32768
  int j = tid & 1023, b = tid >> 10;
  int dir = j >> 9, jj = j & 511;
  size_t si = ((size_t)dir*32 + b)*512 + jj;
  dh[(size_t)b*1024 + j]  = hfin[si];
  dcc[(size_t)b*1024 + j] = cfin[si];
}

// ---------------------------------------------------------------------------
// Batched attention (phase B)
// ---------------------------------------------------------------------------
__global__ __launch_bounds__(256)
void k_attn(const float* __restrict__ Hall,    // [64][32][1024]
            const float* __restrict__ encout,  // [32][64][1024]
            const int* __restrict__ src,
            float* __restrict__ hctx)          // [2048][2048]
{
  int bid = blockIdx.x;
  int t = bid >> 5, b = bid & 31;
  int tid = threadIdx.x;
  __shared__ float sh[1024];
  __shared__ float ssc[64];
  const float* h = Hall + ((size_t)t*32 + b)*1024;
  size_t row = (size_t)t*32 + b;
  #pragma unroll
  for (int r=0;r<4;r++) {
    int jh = tid + 256*r;
    float v = h[jh];
    sh[jh] = v;
    hctx[row*2048 + jh] = v;
  }
  __syncthreads();
  {
    int tq = tid >> 2, part = tid & 3;
    const float* eo = encout + ((size_t)b*64 + tq)*1024 + part*256;
    const float* hh = sh + part*256;
    float s = 0.f;
    for (int k=0;k<256;k++) s = fmaf(hh[k], eo[k], s);
    s += __shfl_xor(s, 1);
    s += __shfl_xor(s, 2);
    if (part == 0) ssc[tq] = (src[b*TSRC + tq] == 0) ? -1e9f : s;
  }
  __syncthreads();
  if (tid < 64) {
    float v = ssc[tid];
    float m = v;
    for (int d=1; d<64; d<<=1) m = fmaxf(m, __shfl_xor(m, d));
    float e = expf(v - m);
    float su = e;
    for (int d=1; d<64; d<<=1) su += __shfl_xor(su, d);
    ssc[tid] = e / su;
  }
  __syncthreads();
  #pragma unroll
  for (int r=0;r<4;r++) {
    int k = tid + 256*r;
    float a = 0.f;
    const float* eb = encout + (size_t)b*65536 + k;
    for (int tt=0;tt<64;tt++) a = fmaf(ssc[tt], eb[tt*1024], a);
    hctx[row*2048 + 1024 + k] = a;
  }
}

// Final: loss = sum(nll)/denom
__global__ __launch_bounds__(256)
void k_final(const float* __restrict__ nll, const int* __restrict__ trg,
             float* __restrict__ outp)
{
  int tid = threadIdx.x;
  __shared__ float ss[256]; __shared__ int sc[256];
  float s = 0.f; int cnt = 0;
  for (int i=tid; i<2048; i+=256) {
    s += nll[i];
    int b = i >> 6, t = (i & 63) + 1;
    cnt += (trg[b*TTRG + t] != 0);
  }
  ss[tid]=s; sc[tid]=cnt; __syncthreads();
  for (int off=128; off; off>>=1) {
    if (tid<off) { ss[tid]+=ss[tid+off]; sc[tid]+=sc[tid+off]; }
    __syncthreads();
  }
  if (tid==0) outp[0] = ss[0] / (float)sc[0];
}

// ---------------------------------------------------------------------------
static void launch_big(hipStream_t st, const float* A, int lda,
                       const float* Bw, int ldb, const float* bias,
                       float* C, int ldc, int M, int N, int K, int act)
{
  GArgs a;
  a.A=A; a.lda=lda;
  a.Bw=Bw; a.ldb=ldb;
  a.bias=bias;
  a.C=C; a.ldc=ldc;
  a.N=N; a.K=K; a.nNb=(N+127)/128; a.act=act;
  dim3 g((M/128)*a.nNb, 1, 1);
  k_gemm<128,128,16,8,8><<<g, dim3(256), 0, st>>>(a);
}

static void launch_med(hipStream_t st, const float* A, int lda,
                       const float* Bw, int ldb, const float* bias,
                       float* C, int ldc, int M, int N, int K, int act)
{
  GArgs a;
  a.A=A; a.lda=lda;
  a.Bw=Bw; a.ldb=ldb;
  a.bias=bias;
  a.C=C; a.ldc=ldc;
  a.N=N; a.K=K; a.nNb=(N+63)/64; a.act=act;
  dim3 g((M/64)*a.nNb, 1, 1);
  k_gemm<64,64,16,4,4><<<g, dim3(256), 0, st>>>(a);
}

extern "C" void kernel_launch(void* const* d_in, const int* in_sizes, int n_in,
                              void* d_out, int out_size, void* d_ws, size_t ws_size,
                              hipStream_t stream)
{
  (void)in_sizes; (void)n_in; (void)out_size; (void)ws_size;
  const int*   src   = (const int*)  d_in[0];
  const int*   trg   = (const int*)  d_in[1];
  const float* semb  = (const float*)d_in[2];
  const float* temb  = (const float*)d_in[3];
  const float* e0Wih = (const float*)d_in[4];
  const float* e0Whh = (const float*)d_in[5];
  const float* e0b   = (const float*)d_in[6];
  const float* e1Wih = (const float*)d_in[7];
  const float* e1Whh = (const float*)d_in[8];
  const float* e1b   = (const float*)d_in[9];
  const float* dWih  = (const float*)d_in[10];
  const float* dWhh  = (const float*)d_in[11];
  const float* db    = (const float*)d_in[12];
  const float* W1    = (const float*)d_in[13];
  const float* W2    = (const float*)d_in[14];
  float* out = (float*)d_out;   // f32 output

  float* ws = (float*)d_ws;
  size_t o = 0;
  float* x_in   = ws + o; o += (size_t)2048*512;    // emb; later: zt
  float* xg     = ws + o; o += (size_t)2048*4096;   // xg; later: hctx + partials
  float* x1     = ws + o; o += (size_t)2048*1024;   // layer-1 input; later: Hall
  float* encout = ws + o; o += (size_t)2048*1024;
  float* hA     = ws + o; o += 2*32*512;
  float* hB     = ws + o; o += 2*32*512;
  float* cbuf   = ws + o; o += 2*32*512;
  float* dh0    = ws + o; o += 32*1024;
  float* dc     = ws + o; o += 32*1024;
  float* nll    = ws + o; o += 2048;
  float* Hall   = x1;                        // [64][32][1024]
  float* hctx   = xg;                        // [2048][2048]
  float* zt     = x_in;                      // [2048][512]
  float* Pmax   = xg + (size_t)4*1024*1024;             // [2048][125]
  int*   Parg   = (int*)(Pmax + (size_t)2048*NTILE);    // [2048][125]
  float* Psum   = Pmax + (size_t)2*2048*NTILE;          // [2048][125]
  float* Ltgt   = Pmax + (size_t)3*2048*NTILE;          // [2048]

  // ---- encoder layer 0 ----
  hipMemsetAsync(hA,   0, 2*32*512*sizeof(float), stream);
  hipMemsetAsync(cbuf, 0, 2*32*512*sizeof(float), stream);
  k_gather<<<dim3(2048), dim3(128), 0, stream>>>(semb, src, x_in, TSRC);
  launch_big(stream, x_in, 512, e0Wih, 512, e0b, xg, 4096, 2048, 4096, 512, 0);
  for (int s=0; s<64; s++) {
    float* hin  = (s&1) ? hB : hA;
    float* hout = (s&1) ? hA : hB;
    k_estep<<<dim3(256), dim3(256), 0, stream>>>(e0Whh, xg, hin, hout, cbuf, x1, s, 0);
  }
  k_pack<<<dim3(128), dim3(256), 0, stream>>>(hA, cbuf, dh0, dc);

  // ---- encoder layer 1 ----
  hipMemsetAsync(hA,   0, 2*32*512*sizeof(float), stream);
  hipMemsetAsync(cbuf, 0, 2*32*512*sizeof(float), stream);
  launch_big(stream, x1, 1024, e1Wih, 1024, e1b, xg, 4096, 2048, 4096, 1024, 0);
  for (int s=0; s<64; s++) {
    float* hin  = (s&1) ? hB : hA;
    float* hout = (s&1) ? hA : hB;
    k_estep<<<dim3(256), dim3(256), 0, stream>>>(e1Whh, xg, hin, hout, cbuf, encout, s, 1);
  }

  // ---- decoder phase A: sequential recurrence into Hall (1 launch/step) ----
  k_gather<<<dim3(2048), dim3(128), 0, stream>>>(temb, trg, x_in, TTRG);
  launch_big(stream, x_in, 512, dWih, 512, db, xg, 4096, 2048, 4096, 512, 0);
  for (int st=0; st<64; st++) {
    const float* hin = (st == 0) ? dh0 : (Hall + (size_t)(st-1)*32*1024);
    k_dstep<<<dim3(256), dim3(256), 0, stream>>>(dWhh, xg + (size_t)st*32*4096,
                 hin, dc, Hall + (size_t)st*32*1024, trg, st);
  }

  // ---- decoder phase B: batched attention + projections + fused logits ----
  k_attn<<<dim3(2048), dim3(256), 0, stream>>>(Hall, encout, src, hctx);
  launch_med(stream, hctx, 2048, W1, 2048, nullptr, zt, 512, 2048, 512, 2048, 1);
  k_logits<<<dim3(2048), dim3(256), 0, stream>>>(zt, W2, trg, Pmax, Parg, Psum, Ltgt);
  k_combine<<<dim3(2048), dim3(128), 0, stream>>>(Pmax, Parg, Psum, Ltgt, trg, nll, out);
  k_final<<<dim3(1), dim3(256), 0, stream>>>(nll, trg, out);
}

// Round 14
// 4118.237 us; speedup vs baseline: 2.3606x; 1.0346x over previous
//
#include <hip/hip_runtime.h>
#include <hip/hip_bf16.h>
#include <math.h>

// Problem constants (B=32, Ts=64, Tt=66, E=H=512, V=16000)
#define TSRC 64
#define TTRG 66
#define NVOC 15996   // V-4
#define NTILE 125    // ceil(15996/128)

__device__ __forceinline__ float sigm(float x){ return 1.f/(1.f+expf(-x)); }

// ---------------------------------------------------------------------------
// Input GEMM 128x128 tile, conflict-free dual-float4 fragments.
// C = A[M,K] * B[N,K]^T + bias. Cols/rows per thread: {g*4+j, 64+g*4+j}.
// ---------------------------------------------------------------------------
__global__ __launch_bounds__(256)
void k_gemm128(const float* __restrict__ A, int lda,
               const float* __restrict__ Bw, int ldb,
               const float* __restrict__ bias,
               float* __restrict__ C, int ldc, int K, int nNb)
{
  const int tid = threadIdx.x;
  const int mb = blockIdx.x / nNb;
  const int nb = blockIdx.x % nNb;
  const int m0 = mb*128, n0 = nb*128;

  __shared__ alignas(16) float As[16][132];
  __shared__ alignas(16) float Bs[16][132];
  const int tx = tid & 15;
  const int ty = tid >> 4;
  float acc[8][8];
  #pragma unroll
  for (int i=0;i<8;i++)
    #pragma unroll
    for (int j=0;j<8;j++) acc[i][j]=0.f;

  for (int kt=0; kt<K; kt+=16) {
    #pragma unroll
    for (int i=tid; i<128*16; i+=256) {
      int m = i>>4, k = i&15;
      As[k][m] = A[(size_t)(m0+m)*lda + kt + k];
    }
    #pragma unroll
    for (int i=tid; i<128*16; i+=256) {
      int n = i>>4, k = i&15;
      Bs[k][n] = Bw[(size_t)(n0+n)*ldb + kt + k];
    }
    __syncthreads();
    #pragma unroll
    for (int k=0;k<16;k++) {
      float4 a0 = *reinterpret_cast<const float4*>(&As[k][ty*4]);
      float4 a1 = *reinterpret_cast<const float4*>(&As[k][64+ty*4]);
      float4 b0 = *reinterpret_cast<const float4*>(&Bs[k][tx*4]);
      float4 b1 = *reinterpret_cast<const float4*>(&Bs[k][64+tx*4]);
      float av[8] = {a0.x,a0.y,a0.z,a0.w,a1.x,a1.y,a1.z,a1.w};
      float bv[8] = {b0.x,b0.y,b0.z,b0.w,b1.x,b1.y,b1.z,b1.w};
      #pragma unroll
      for (int i=0;i<8;i++)
        #pragma unroll
        for (int j=0;j<8;j++)
          acc[i][j] = fmaf(av[i], bv[j], acc[i][j]);
    }
    __syncthreads();
  }
  #pragma unroll
  for (int i=0;i<8;i++) {
    int m = m0 + ((i<4) ? ty*4+i : 64+ty*4+(i-4));
    int nA = n0 + tx*4, nB = n0 + 64 + tx*4;
    float4 v0, v1;
    v0.x = acc[i][0] + (bias?bias[nA+0]:0.f);
    v0.y = acc[i][1] + (bias?bias[nA+1]:0.f);
    v0.z = acc[i][2] + (bias?bias[nA+2]:0.f);
    v0.w = acc[i][3] + (bias?bias[nA+3]:0.f);
    v1.x = acc[i][4] + (bias?bias[nB+0]:0.f);
    v1.y = acc[i][5] + (bias?bias[nB+1]:0.f);
    v1.z = acc[i][6] + (bias?bias[nB+2]:0.f);
    v1.w = acc[i][7] + (bias?bias[nB+3]:0.f);
    *reinterpret_cast<float4*>(&C[(size_t)m*ldc + nA]) = v0;
    *reinterpret_cast<float4*>(&C[(size_t)m*ldc + nB]) = v1;
  }
}

// ---------------------------------------------------------------------------
// Fused logits GEMM + per-tile row reduction, conflict-free fragments.
// XCD-swizzled: all 16 row-blocks sharing a W2 tile land on one XCD.
// ---------------------------------------------------------------------------
__global__ __launch_bounds__(256)
void k_logits(const float* __restrict__ A, const float* __restrict__ Bw,
              const int* __restrict__ trg,
              float* __restrict__ Pmax, int* __restrict__ Parg,
              float* __restrict__ Psum, float* __restrict__ Ltgt)
{
  const int tid = threadIdx.x;
  const int j8   = blockIdx.x & 7;
  const int mb   = (blockIdx.x >> 3) & 15;
  const int nb   = ((blockIdx.x >> 7) << 3) + j8;
  if (nb >= NTILE) return;
  const int m0 = mb*128, n0 = nb*128;

  __shared__ alignas(16) float As[16][132];
  __shared__ alignas(16) float Bs[16][132];
  const int tx = tid & 15;
  const int ty = tid >> 4;
  float acc[8][8];
  #pragma unroll
  for (int i=0;i<8;i++)
    #pragma unroll
    for (int j=0;j<8;j++) acc[i][j]=0.f;

  for (int kt=0; kt<512; kt+=16) {
    #pragma unroll
    for (int i=tid; i<128*16; i+=256) {
      int m = i>>4, k = i&15;
      As[k][m] = A[(size_t)(m0+m)*512 + kt + k];
    }
    #pragma unroll
    for (int i=tid; i<128*16; i+=256) {
      int n = i>>4, k = i&15;
      int gn = n0+n;
      Bs[k][n] = (gn < NVOC) ? Bw[(size_t)gn*512 + kt + k] : 0.f;
    }
    __syncthreads();
    #pragma unroll
    for (int k=0;k<16;k++) {
      float4 a0 = *reinterpret_cast<const float4*>(&As[k][ty*4]);
      float4 a1 = *reinterpret_cast<const float4*>(&As[k][64+ty*4]);
      float4 b0 = *reinterpret_cast<const float4*>(&Bs[k][tx*4]);
      float4 b1 = *reinterpret_cast<const float4*>(&Bs[k][64+tx*4]);
      float av[8] = {a0.x,a0.y,a0.z,a0.w,a1.x,a1.y,a1.z,a1.w};
      float bv[8] = {b0.x,b0.y,b0.z,b0.w,b1.x,b1.y,b1.z,b1.w};
      #pragma unroll
      for (int i=0;i<8;i++)
        #pragma unroll
        for (int j=0;j<8;j++)
          acc[i][j] = fmaf(av[i], bv[j], acc[i][j]);
    }
    __syncthreads();
  }

  #pragma unroll
  for (int i=0;i<8;i++) {
    int r = m0 + ((i<4) ? ty*4+i : 64+ty*4+(i-4));   // row = step*32 + b
    int step = r >> 5, b = r & 31;
    int tgt = trg[b*TTRG + step + 1];
    int ti = tgt - 4;
    float m = -3.4e38f; int am = 0x7fffffff;
    #pragma unroll
    for (int j=0;j<8;j++) {
      int gn = n0 + ((j<4) ? tx*4+j : 64+tx*4+(j-4));
      if (gn < NVOC) {
        float x = acc[i][j];
        if (x > m || (x == m && gn < am)) { m = x; am = gn; }
      }
    }
    float s = 0.f;
    float lt = 0.f;
    #pragma unroll
    for (int j=0;j<8;j++) {
      int gn = n0 + ((j<4) ? tx*4+j : 64+tx*4+(j-4));
      if (gn < NVOC) {
        s += expf(acc[i][j] - m);
        if (gn == ti) lt = acc[i][j];
      }
    }
    #pragma unroll
    for (int d=1; d<16; d<<=1) {
      float m2 = __shfl_xor(m, d);
      int   a2 = __shfl_xor(am, d);
      float s2 = __shfl_xor(s, d);
      float l2 = __shfl_xor(lt, d);
      float M = fmaxf(m, m2);
      s = s*expf(m - M) + s2*expf(m2 - M);
      if (m2 > m || (m2 == m && a2 < am)) am = a2;
      m = M;
      lt += l2;
    }
    if (tx == 0) {
      size_t pi = (size_t)r*NTILE + nb;
      Pmax[pi] = m; Parg[pi] = am; Psum[pi] = s;
      if (ti >= n0 && ti < n0 + 128) Ltgt[r] = lt;
    }
  }
}

// ---------------------------------------------------------------------------
// Tiled GEMM (64x64, used for W1 only): C = A*B^T, tanh epilogue.
// ---------------------------------------------------------------------------
struct GArgs {
  const float* A;  int lda;
  const float* Bw; int ldb;
  const float* bias;
  float* C; int ldc;
  int N; int K; int nNb; int act;
};

template<int BM,int BN,int BK,int TM,int TN>
__global__ __launch_bounds__(256)
void k_gemm(GArgs a)
{
  const int tid = threadIdx.x;
  const int mb = blockIdx.x / a.nNb;
  const int nb = blockIdx.x % a.nNb;
  const int m0 = mb*BM, n0 = nb*BN;
  const float* A  = a.A + (size_t)m0*a.lda;
  const float* Bw = a.Bw;

  __shared__ float As[BK][BM+1];
  __shared__ float Bs[BK][BN+4];
  const int tx = tid % (BN/TN);
  const int ty = tid / (BN/TN);
  float acc[TM][TN];
  #pragma unroll
  for (int i=0;i<TM;i++)
    #pragma unroll
    for (int j=0;j<TN;j++) acc[i][j]=0.f;

  for (int kt=0; kt<a.K; kt+=BK) {
    #pragma unroll
    for (int i=tid; i<BM*BK; i+=256) {
      int m = i/BK, k = i%BK;
      As[k][m] = A[(size_t)m*a.lda + kt + k];
    }
    #pragma unroll
    for (int i=tid; i<BN*BK; i+=256) {
      int n = i/BK, k = i%BK;
      int gn = n0+n;
      Bs[k][n] = (gn < a.N) ? Bw[(size_t)gn*a.ldb + kt + k] : 0.f;
    }
    __syncthreads();
    #pragma unroll
    for (int k=0;k<BK;k++) {
      float av[TM], bv[TN];
      #pragma unroll
      for (int i=0;i<TM;i++) av[i]=As[k][ty*TM+i];
      #pragma unroll
      for (int j=0;j<TN;j++) bv[j]=Bs[k][tx*TN+j];
      #pragma unroll
      for (int i=0;i<TM;i++)
        #pragma unroll
        for (int j=0;j<TN;j++)
          acc[i][j] = fmaf(av[i], bv[j], acc[i][j]);
    }
    __syncthreads();
  }
  #pragma unroll
  for (int i=0;i<TM;i++) {
    int m = m0 + ty*TM + i;
    #pragma unroll
    for (int j=0;j<TN;j++) {
      int n = n0 + tx*TN + j;
      if (n < a.N) {
        float v = acc[i][j];
        if (a.bias) v += a.bias[n];
        if (a.act)  v = tanhf(v);
        a.C[(size_t)m*a.ldc + n] = v;
      }
    }
  }
}

// Combine per-tile partials -> nll + pred per row.
__global__ __launch_bounds__(128)
void k_combine(const float* __restrict__ Pmax, const int* __restrict__ Parg,
               const float* __restrict__ Psum, const float* __restrict__ Ltgt,
               const int* __restrict__ trg,
               float* __restrict__ nll, float* __restrict__ outp)
{
  int r = blockIdx.x;
  int step = r >> 5, b = r & 31;
  int tid = threadIdx.x;
  __shared__ float sm[128]; __shared__ int sa[128]; __shared__ float ssum[128];
  float m = -3.4e38f; int am = 0x7fffffff; float s = 0.f;
  if (tid < NTILE) {
    size_t pi = (size_t)r*NTILE + tid;
    m = Pmax[pi]; am = Parg[pi]; s = Psum[pi];
  }
  sm[tid]=m; sa[tid]=am; ssum[tid]=s; __syncthreads();
  for (int off=64; off; off>>=1) {
    if (tid < off) {
      float m2 = sm[tid+off]; int a2 = sa[tid+off]; float s2 = ssum[tid+off];
      float m1 = sm[tid];     int a1 = sa[tid];     float s1 = ssum[tid];
      float M = fmaxf(m1, m2);
      ssum[tid] = s1*expf(m1 - M) + s2*expf(m2 - M);
      if (m2 > m1 || (m2 == m1 && a2 < a1)) sa[tid] = a2;
      sm[tid] = M;
    }
    __syncthreads();
  }
  if (tid == 0) {
    int tgt = trg[b*TTRG + step + 1];
    float nl = 0.f;
    if (tgt != 0) nl = -(Ltgt[r] - sm[0] - logf(ssum[0]));
    nll[step*32 + b] = nl;
    outp[1 + b*64 + step] = (float)(sa[0] + 4);
  }
}

// Embedding gather
__global__ void k_gather(const float* __restrict__ emb, const int* __restrict__ tok,
                         float* __restrict__ outp, int Tfull)
{
  int r = blockIdx.x;
  int t = r >> 5, b = r & 31;
  int token = tok[b*Tfull + t];
  const float4* s = (const float4*)(emb + (size_t)token*512);
  float4* d = (float4*)(outp + (size_t)r*512);
  d[threadIdx.x] = s[threadIdx.x];
}

// ---------------------------------------------------------------------------
// FUSED encoder LSTM step (ONE launch): full-K gates + update + scatter.
// ---------------------------------------------------------------------------
__global__ __launch_bounds__(256)
void k_estep(const float* __restrict__ Whh,   // [2][2048][512]
             const float* __restrict__ xg,    // [2048][4096]
             const float* __restrict__ hin,   // [2*32][512]
             float* __restrict__ hout,        // [2*32][512]
             float* __restrict__ cst,         // [2*32][512]
             float* __restrict__ xout, int s, int mode)
{
  const int bid = blockIdx.x;
  const int dir = bid >> 7;
  const int j0  = (bid & 127) * 4;
  const int tid = threadIdx.x;
  const int kg  = tid >> 5;
  const int b   = tid & 31;
  __shared__ float4 wl4[16*128];
  __shared__ float red[4*16*33];

  {
    const float* W = Whh + (size_t)dir*2048*512;
    for (int idx = tid; idx < 16*128; idx += 256) {
      int r = idx >> 7, c = idx & 127;
      int g = r >> 2, jj = r & 3;
      wl4[idx] = ((const float4*)(W + (size_t)(g*512 + j0 + jj)*512))[c];
    }
  }
  float4 hreg[16];
  {
    const float4* H4 = (const float4*)(hin + (size_t)dir*32*512);
    #pragma unroll
    for (int j=0;j<16;j++) hreg[j] = H4[(size_t)b*128 + kg*16 + j];
  }
  __syncthreads();

  float acc[16];
  #pragma unroll
  for (int r=0;r<16;r++) {
    const float4* wr = wl4 + r*128 + kg*16;
    float a0=0.f,a1=0.f,a2=0.f,a3=0.f;
    #pragma unroll
    for (int j=0;j<16;j++) {
      float4 w = wr[j];
      a0 = fmaf(w.x, hreg[j].x, a0);
      a1 = fmaf(w.y, hreg[j].y, a1);
      a2 = fmaf(w.z, hreg[j].z, a2);
      a3 = fmaf(w.w, hreg[j].w, a3);
    }
    acc[r] = (a0+a1)+(a2+a3);
  }
  #pragma unroll
  for (int r=0;r<16;r++) acc[r] += __shfl_xor(acc[r], 32);
  const int wv = tid >> 6;
  if ((tid & 32) == 0) {
    #pragma unroll
    for (int r=0;r<16;r++) red[wv*528 + r*33 + b] = acc[r];
  }
  __syncthreads();

  if (tid < 128) {
    int jj = tid >> 5, bb = tid & 31;
    int jh = j0 + jj;
    int t  = dir ? (63 - s) : s;
    const float* x = xg + ((size_t)t*32 + bb)*4096 + dir*2048;
    float g4[4];
    #pragma unroll
    for (int g=0; g<4; g++) {
      int r = g*4 + jj;
      g4[g] = ((red[0*528 + r*33 + bb] + red[1*528 + r*33 + bb])
             + (red[2*528 + r*33 + bb] + red[3*528 + r*33 + bb]))
             + x[g*512 + jh];
    }
    size_t ci = ((size_t)dir*32 + bb)*512 + jh;
    float cn = sigm(g4[1])*cst[ci] + sigm(g4[0])*tanhf(g4[2]);
    float hn = sigm(g4[3])*tanhf(cn);
    cst[ci] = cn;
    hout[ci] = hn;
    if (mode == 0) xout[((size_t)t*32 + bb)*1024 + dir*512 + jh] = hn;  // x1
    else           xout[((size_t)bb*64 + t)*1024 + dir*512 + jh] = hn;  // enc_out
  }
}

// ---------------------------------------------------------------------------
// FUSED decoder LSTM step (ONE launch): full-K gates + update + mask -> Hall.
// ---------------------------------------------------------------------------
__global__ __launch_bounds__(256)
void k_dstep(const float* __restrict__ Whh,   // [4096][1024]
             const float* __restrict__ xg_t,  // [32][4096] this step
             const float* __restrict__ hin,   // [32][1024]
             float* __restrict__ cst,         // [32][1024]
             float* __restrict__ hall_t,      // [32][1024]
             const int* __restrict__ trg, int st)
{
  const int bid = blockIdx.x;
  const int j0  = bid*4;
  const int tid = threadIdx.x;
  const int kg  = tid >> 5;
  const int b   = tid & 31;
  __shared__ float4 wl4[8*256];
  __shared__ float red[4*16*33];

  float4 hreg[32];
  {
    const float4* H4 = (const float4*)hin;
    #pragma unroll
    for (int j=0;j<32;j++) hreg[j] = H4[(size_t)b*256 + kg*32 + j];
  }

  float acc[16];
  #pragma unroll
  for (int hh=0; hh<2; hh++) {
    for (int idx = tid; idx < 8*256; idx += 256) {
      int rl = idx >> 8, c = idx & 255;
      int r = hh*8 + rl;
      int g = r >> 2, jj = r & 3;
      wl4[idx] = ((const float4*)(Whh + (size_t)(g*1024 + j0 + jj)*1024))[c];
    }
    __syncthreads();
    #pragma unroll
    for (int rl=0; rl<8; rl++) {
      const float4* wr = wl4 + rl*256 + kg*32;
      float a0=0.f,a1=0.f,a2=0.f,a3=0.f;
      #pragma unroll
      for (int j=0;j<32;j++) {
        float4 w = wr[j];
        a0 = fmaf(w.x, hreg[j].x, a0);
        a1 = fmaf(w.y, hreg[j].y, a1);
        a2 = fmaf(w.z, hreg[j].z, a2);
        a3 = fmaf(w.w, hreg[j].w, a3);
      }
      acc[hh*8 + rl] = (a0+a1)+(a2+a3);
    }
    __syncthreads();
  }
  #pragma unroll
  for (int r=0;r<16;r++) acc[r] += __shfl_xor(acc[r], 32);
  const int wv = tid >> 6;
  if ((tid & 32) == 0) {
    #pragma unroll
    for (int r=0;r<16;r++) red[wv*528 + r*33 + b] = acc[r];
  }
  __syncthreads();

  if (tid < 128) {
    int jj = tid >> 5, bb = tid & 31;
    int jh = j0 + jj;
    int tgt = trg[bb*TTRG + st + 1];
    bool dm = (tgt == 0);
    const float* x = xg_t + (size_t)bb*4096;
    float g4[4];
    #pragma unroll
    for (int g=0; g<4; g++) {
      int r = g*4 + jj;
      g4[g] = ((red[0*528 + r*33 + bb] + red[1*528 + r*33 + bb])
             + (red[2*528 + r*33 + bb] + red[3*528 + r*33 + bb]))
             + x[g*1024 + jh];
    }
    size_t ci = (size_t)bb*1024 + jh;
    float cn = sigm(g4[1])*cst[ci] + sigm(g4[0])*tanhf(g4[2]);
    float hn = sigm(g4[3])*tanhf(cn);
    cst[ci] = cn;                    // cell NOT masked (matches reference)
    hall_t[ci] = dm ? 0.f : hn;      // h masked
  }
}

// Pack layer-0 final states into decoder initial h/c
__global__ void k_pack(const float* __restrict__ hfin, const float* __restrict__ cfin,
                       float* __restrict__ dh, float* __restrict__ dcc)
{
  int tid = blockIdx.x*256 + threadIdx.x;   // 32768
  int j = tid & 1023, b = tid >> 10;
  int dir = j >> 9, jj = j & 511;
  size_t si = ((size_t)dir*32 + b)*512 + jj;
  dh[(size_t)b*1024 + j]  = hfin[si];
  dcc[(size_t)b*1024 + j] = cfin[si];
}

// ---------------------------------------------------------------------------
// Batched attention (phase B)
// ---------------------------------------------------------------------------
__global__ __launch_bounds__(256)
void k_attn(const float* __restrict__ Hall,    // [64][32][1024]
            const float* __restrict__ encout,  // [32][64][1024]
            const int* __restrict__ src,
            float* __restrict__ hctx)          // [2048][2048]
{
  int bid = blockIdx.x;
  int t = bid >> 5, b = bid & 31;
  int tid = threadIdx.x;
  __shared__ float sh[1024];
  __shared__ float ssc[64];
  const float* h = Hall + ((size_t)t*32 + b)*1024;
  size_t row = (size_t)t*32 + b;
  #pragma unroll
  for (int r=0;r<4;r++) {
    int jh = tid + 256*r;
    float v = h[jh];
    sh[jh] = v;
    hctx[row*2048 + jh] = v;
  }
  __syncthreads();
  {
    int tq = tid >> 2, part = tid & 3;
    const float* eo = encout + ((size_t)b*64 + tq)*1024 + part*256;
    const float* hh = sh + part*256;
    float s = 0.f;
    for (int k=0;k<256;k++) s = fmaf(hh[k], eo[k], s);
    s += __shfl_xor(s, 1);
    s += __shfl_xor(s, 2);
    if (part == 0) ssc[tq] = (src[b*TSRC + tq] == 0) ? -1e9f : s;
  }
  __syncthreads();
  if (tid < 64) {
    float v = ssc[tid];
    float m = v;
    for (int d=1; d<64; d<<=1) m = fmaxf(m, __shfl_xor(m, d));
    float e = expf(v - m);
    float su = e;
    for (int d=1; d<64; d<<=1) su += __shfl_xor(su, d);
    ssc[tid] = e / su;
  }
  __syncthreads();
  #pragma unroll
  for (int r=0;r<4;r++) {
    int k = tid + 256*r;
    float a = 0.f;
    const float* eb = encout + (size_t)b*65536 + k;
    for (int tt=0;tt<64;tt++) a = fmaf(ssc[tt], eb[tt*1024], a);
    hctx[row*2048 + 1024 + k] = a;
  }
}

// Final: loss = sum(nll)/denom
__global__ __launch_bounds__(256)
void k_final(const float* __restrict__ nll, const int* __restrict__ trg,
             float* __restrict__ outp)
{
  int tid = threadIdx.x;
  __shared__ float ss[256]; __shared__ int sc[256];
  float s = 0.f; int cnt = 0;
  for (int i=tid; i<2048; i+=256) {
    s += nll[i];
    int b = i >> 6, t = (i & 63) + 1;
    cnt += (trg[b*TTRG + t] != 0);
  }
  ss[tid]=s; sc[tid]=cnt; __syncthreads();
  for (int off=128; off; off>>=1) {
    if (tid<off) { ss[tid]+=ss[tid+off]; sc[tid]+=sc[tid+off]; }
    __syncthreads();
  }
  if (tid==0) outp[0] = ss[0] / (float)sc[0];
}

// ---------------------------------------------------------------------------
static void launch_big(hipStream_t st, const float* A, int lda,
                       const float* Bw, int ldb, const float* bias,
                       float* C, int ldc, int M, int N, int K)
{
  int nNb = N/128;
  dim3 g((M/128)*nNb, 1, 1);
  k_gemm128<<<g, dim3(256), 0, st>>>(A, lda, Bw, ldb, bias, C, ldc, K, nNb);
}

static void launch_med(hipStream_t st, const float* A, int lda,
                       const float* Bw, int ldb, const float* bias,
                       float* C, int ldc, int M, int N, int K, int act)
{
  GArgs a;
  a.A=A; a.lda=lda;
  a.Bw=Bw; a.ldb=ldb;
  a.bias=bias;
  a.C=C; a.ldc=ldc;
  a.N=N; a.K=K; a.nNb=(N+63)/64; a.act=act;
  dim3 g((M/64)*a.nNb, 1, 1);
  k_gemm<64,64,16,4,4><<<g, dim3(256), 0, st>>>(a);
}

extern "C" void kernel_launch(void* const* d_in, const int* in_sizes, int n_in,
                              void* d_out, int out_size, void* d_ws, size_t ws_size,
                              hipStream_t stream)
{
  (void)in_sizes; (void)n_in; (void)out_size; (void)ws_size;
  const int*   src   = (const int*)  d_in[0];
  const int*   trg   = (const int*)  d_in[1];
  const float* semb  = (const float*)d_in[2];
  const float* temb  = (const float*)d_in[3];
  const float* e0Wih = (const float*)d_in[4];
  const float* e0Whh = (const float*)d_in[5];
  const float* e0b   = (const float*)d_in[6];
  const float* e1Wih = (const float*)d_in[7];
  const float* e1Whh = (const float*)d_in[8];
  const float* e1b   = (const float*)d_in[9];
  const float* dWih  = (const float*)d_in[10];
  const float* dWhh  = (const float*)d_in[11];
  const float* db    = (const float*)d_in[12];
  const float* W1    = (const float*)d_in[13];
  const float* W2    = (const float*)d_in[14];
  float* out = (float*)d_out;   // f32 output

  float* ws = (float*)d_ws;
  size_t o = 0;
  float* x_in   = ws + o; o += (size_t)2048*512;    // emb; later: zt
  float* xg     = ws + o; o += (size_t)2048*4096;   // xg; later: hctx + partials
  float* x1     = ws + o; o += (size_t)2048*1024;   // layer-1 input; later: Hall
  float* encout = ws + o; o += (size_t)2048*1024;
  float* hA     = ws + o; o += 2*32*512;
  float* hB     = ws + o; o += 2*32*512;
  float* cbuf   = ws + o; o += 2*32*512;
  float* dh0    = ws + o; o += 32*1024;
  float* dc     = ws + o; o += 32*1024;
  float* nll    = ws + o; o += 2048;
  float* Hall   = x1;                        // [64][32][1024]
  float* hctx   = xg;                        // [2048][2048]
  float* zt     = x_in;                      // [2048][512]
  float* Pmax   = xg + (size_t)4*1024*1024;             // [2048][125]
  int*   Parg   = (int*)(Pmax + (size_t)2048*NTILE);    // [2048][125]
  float* Psum   = Pmax + (size_t)2*2048*NTILE;          // [2048][125]
  float* Ltgt   = Pmax + (size_t)3*2048*NTILE;          // [2048]

  // ---- encoder layer 0 ----
  hipMemsetAsync(hA,   0, 2*32*512*sizeof(float), stream);
  hipMemsetAsync(cbuf, 0, 2*32*512*sizeof(float), stream);
  k_gather<<<dim3(2048), dim3(128), 0, stream>>>(semb, src, x_in, TSRC);
  launch_big(stream, x_in, 512, e0Wih, 512, e0b, xg, 4096, 2048, 4096, 512);
  for (int s=0; s<64; s++) {
    float* hin  = (s&1) ? hB : hA;
    float* hout = (s&1) ? hA : hB;
    k_estep<<<dim3(256), dim3(256), 0, stream>>>(e0Whh, xg, hin, hout, cbuf, x1, s, 0);
  }
  k_pack<<<dim3(128), dim3(256), 0, stream>>>(hA, cbuf, dh0, dc);

  // ---- encoder layer 1 ----
  hipMemsetAsync(hA,   0, 2*32*512*sizeof(float), stream);
  hipMemsetAsync(cbuf, 0, 2*32*512*sizeof(float), stream);
  launch_big(stream, x1, 1024, e1Wih, 1024, e1b, xg, 4096, 2048, 4096, 1024);
  for (int s=0; s<64; s++) {
    float* hin  = (s&1) ? hB : hA;
    float* hout = (s&1) ? hA : hB;
    k_estep<<<dim3(256), dim3(256), 0, stream>>>(e1Whh, xg, hin, hout, cbuf, encout, s, 1);
  }

  // ---- decoder phase A: sequential recurrence into Hall (1 launch/step) ----
  k_gather<<<dim3(2048), dim3(128), 0, stream>>>(temb, trg, x_in, TTRG);
  launch_big(stream, x_in, 512, dWih, 512, db, xg, 4096, 2048, 4096, 512);
  for (int st=0; st<64; st++) {
    const float* hin = (st == 0) ? dh0 : (Hall + (size_t)(st-1)*32*1024);
    k_dstep<<<dim3(256), dim3(256), 0, stream>>>(dWhh, xg + (size_t)st*32*4096,
                 hin, dc, Hall + (size_t)st*32*1024, trg, st);
  }

  // ---- decoder phase B: batched attention + projections + fused logits ----
  k_attn<<<dim3(2048), dim3(256), 0, stream>>>(Hall, encout, src, hctx);
  launch_med(stream, hctx, 2048, W1, 2048, nullptr, zt, 512, 2048, 512, 2048, 1);
  k_logits<<<dim3(2048), dim3(256), 0, stream>>>(zt, W2, trg, Pmax, Parg, Psum, Ltgt);
  k_combine<<<dim3(2048), dim3(128), 0, stream>>>(Pmax, Parg, Psum, Ltgt, trg, nll, out);
  k_final<<<dim3(1), dim3(256), 0, stream>>>(nll, trg, out);
}